// Round 1
// baseline (1360.138 us; speedup 1.0000x reference)
//
#include <hip/hip_runtime.h>
#include <hip/hip_bf16.h>
#include <math.h>

// ============================================================================
// StylePredictor: spectral MLP (mish) -> 2x Conv1dGLU -> mask -> MHSA ->
// out-proj + residual -> fused (pool-then-project) final layer.
// Round 1: correct fp32 baseline. Conv = implicit GEMM over K = 256*5 = 1280.
// ============================================================================

#define DEV __device__ __forceinline__

static constexpr int B_ = 16, T_ = 1024, D_ = 256;
static constexpr int N_ = B_ * T_;           // 16384 rows
static constexpr int C2_ = 2 * D_;           // 512 conv out channels
static constexpr int KW_ = 5;
static constexpr int KKC_ = D_ * KW_;        // 1280 implicit-GEMM K

DEV float sigmoidf_(float x) { return 1.f / (1.f + __expf(-x)); }
DEV float mishf_(float x) {
  float sp = (x > 20.f) ? x : log1pf(expf(x));
  return x * tanhf(sp);
}

// ---------------------------------------------------------------------------
// Mask prep: detect storage layout of the bool mask (int32 / int8 / float32)
// and write fp32 fmask (1.0 = masked/zeroed, 0.0 = keep).
// Detection: scan first 4096 dwords (16KB, safe for all layouts).
//   bytes-layout -> dwords like 0x00010001 (>1); float -> 0x3F800000; else int32.
// ---------------------------------------------------------------------------
__global__ __launch_bounds__(256) void mask_prep_kernel(
    const unsigned* __restrict__ mraw, float* __restrict__ fmask) {
  int tid = threadIdx.x;
  int isByte = 0, isFloat = 0;
  for (int i = 0; i < 16; ++i) {
    unsigned v = mraw[tid * 16 + i];
    if (v == 0x3F800000u) isFloat = 1;
    else if (v > 1u) isByte = 1;
  }
  __shared__ int sByte, sFloat;
  if (tid == 0) { sByte = 0; sFloat = 0; }
  __syncthreads();
  if (isByte) atomicOr(&sByte, 1);
  if (isFloat) atomicOr(&sFloat, 1);
  __syncthreads();
  int mode = sFloat ? 2 : (sByte ? 1 : 0);
  int idx = blockIdx.x * 256 + tid;
  unsigned mv;
  if (mode == 1) mv = ((const unsigned char*)mraw)[idx];
  else           mv = mraw[idx];   // int32 0/1 or float bits (0.0 -> 0)
  fmask[idx] = (mv != 0u) ? 1.f : 0.f;
}

// ---------------------------------------------------------------------------
// Weight transpose for conv implicit GEMM:
//   wt[(k*256+cin)*512 + co] = cw[co*1280 + cin*5 + k]
// so the GEMM K index kk = k*256+cin makes A-tile loads contiguous in cin.
// ---------------------------------------------------------------------------
__global__ __launch_bounds__(256) void transpose_w_kernel(
    const float* __restrict__ cw, float* __restrict__ wt) {
  int i = blockIdx.x * 256 + threadIdx.x;
  if (i >= C2_ * KKC_) return;
  int co = i / KKC_;
  int r = i - co * KKC_;
  int cin = r / KW_;
  int k = r - cin * KW_;
  wt[(size_t)(k * D_ + cin) * C2_ + co] = cw[i];
}

// ---------------------------------------------------------------------------
// Shared 64x64 fp32 tile FMA: As [m][k] row-major (stride 36), Ws [k][n]
// (stride 68). b128 LDS reads, conflict-free/2-way patterns.
// ---------------------------------------------------------------------------
DEV void tile_fma_(const float (*As)[36], const float (*Ws)[68],
                   float acc[4][4], int tx, int ty) {
#pragma unroll
  for (int k4 = 0; k4 < 8; ++k4) {
    float4 b4[4];
#pragma unroll
    for (int kk = 0; kk < 4; ++kk)
      b4[kk] = *(const float4*)&Ws[k4 * 4 + kk][tx * 4];
#pragma unroll
    for (int i = 0; i < 4; ++i) {
      float4 a4 = *(const float4*)&As[ty * 4 + i][k4 * 4];
#pragma unroll
      for (int kk = 0; kk < 4; ++kk) {
        float av = (kk == 0) ? a4.x : (kk == 1) ? a4.y : (kk == 2) ? a4.z : a4.w;
        acc[i][0] += av * b4[kk].x;
        acc[i][1] += av * b4[kk].y;
        acc[i][2] += av * b4[kk].z;
        acc[i][3] += av * b4[kk].w;
      }
    }
  }
}

// ---------------------------------------------------------------------------
// Generic fp32 GEMM: C = act(A @ W^T + bias) [+ resid]
// A [Nrows, Din], W [Dout, Din] (torch Linear layout), C [Nrows, Dout].
// BM=BN=64, BK=32, 256 threads, 4x4 micro-tile. ACT: 0=none, 1=mish.
// ---------------------------------------------------------------------------
template <int ACT, int RESID>
__global__ __launch_bounds__(256) void gemm_kernel(
    const float* __restrict__ A, const float* __restrict__ W,
    const float* __restrict__ bias, const float* __restrict__ resid,
    float* __restrict__ C, int Nrows, int Din, int Dout) {
  __shared__ __align__(16) float As[64][36];
  __shared__ __align__(16) float Ws[32][68];
  int tid = threadIdx.x;
  int tx = tid & 15, ty = tid >> 4;
  int c0 = blockIdx.x * 64;
  int n0 = blockIdx.y * 64;
  float acc[4][4] = {};
  int nkt = Din >> 5;
  for (int kt = 0; kt < nkt; ++kt) {
    int k0 = kt << 5;
    {  // stage A (direct copy, float4 along k)
      int m = tid >> 3, k4 = tid & 7;
      *(float4*)&As[m][k4 * 4] =
          *(const float4*)&A[(size_t)(n0 + m) * Din + k0 + k4 * 4];
      *(float4*)&As[m + 32][k4 * 4] =
          *(const float4*)&A[(size_t)(n0 + m + 32) * Din + k0 + k4 * 4];
    }
    {  // stage W transposed: Ws[k][n] = W[(c0+n)*Din + k0+k]
      int n = tid >> 3, k4 = tid & 7;
      float4 w0 = *(const float4*)&W[(size_t)(c0 + n) * Din + k0 + k4 * 4];
      Ws[k4 * 4 + 0][n] = w0.x; Ws[k4 * 4 + 1][n] = w0.y;
      Ws[k4 * 4 + 2][n] = w0.z; Ws[k4 * 4 + 3][n] = w0.w;
      float4 w1 = *(const float4*)&W[(size_t)(c0 + n + 32) * Din + k0 + k4 * 4];
      Ws[k4 * 4 + 0][n + 32] = w1.x; Ws[k4 * 4 + 1][n + 32] = w1.y;
      Ws[k4 * 4 + 2][n + 32] = w1.z; Ws[k4 * 4 + 3][n + 32] = w1.w;
    }
    __syncthreads();
    tile_fma_(As, Ws, acc, tx, ty);
    __syncthreads();
  }
  float4 bv = *(const float4*)&bias[c0 + tx * 4];
#pragma unroll
  for (int i = 0; i < 4; ++i) {
    int row = n0 + ty * 4 + i;
    float4 c;
    c.x = acc[i][0] + bv.x; c.y = acc[i][1] + bv.y;
    c.z = acc[i][2] + bv.z; c.w = acc[i][3] + bv.w;
    if (ACT == 1) { c.x = mishf_(c.x); c.y = mishf_(c.y); c.z = mishf_(c.z); c.w = mishf_(c.w); }
    if (RESID) {
      float4 r = *(const float4*)&resid[(size_t)row * Dout + c0 + tx * 4];
      c.x += r.x; c.y += r.y; c.z += r.z; c.w += r.w;
    }
    *(float4*)&C[(size_t)row * Dout + c0 + tx * 4] = c;
  }
}

// ---------------------------------------------------------------------------
// Conv1dGLU as implicit GEMM. Hin [B,T,256]. Wt [1280][512] (kk = k*256+cin).
// Block: 64 rows x (32 a-channels + 32 matching g-channels). K-loop of 40x32.
// A-tile = Hin rows shifted by (k-2) with zero padding at t boundaries.
// Epilogue: y through LDS, out = Hin + (y_a+cb_a)*sigmoid(y_g+cb_g), optional
// mask-zeroing fused (DO_MASK for the second block).
// ---------------------------------------------------------------------------
template <int DO_MASK>
__global__ __launch_bounds__(256) void conv_glu_kernel(
    const float* __restrict__ Hin, const float* __restrict__ Wt,
    const float* __restrict__ cb, const float* __restrict__ fmask,
    float* __restrict__ Hout) {
  __shared__ __align__(16) float As[64][36];
  __shared__ __align__(16) float Ws[32][68];
  __shared__ __align__(16) float Yt[64][68];
  int tid = threadIdx.x;
  int tx = tid & 15, ty = tid >> 4;
  int cg = blockIdx.x;            // channel group 0..7 (32 a-ch each)
  int n0 = blockIdx.y * 64;
  float acc[4][4] = {};
  for (int kt = 0; kt < 40; ++kt) {
    int ksl = kt >> 3;            // conv tap 0..4
    int cin0 = (kt & 7) << 5;     // cin chunk base
    {  // stage A with temporal shift + zero pad
      int m = tid >> 3, k4 = tid & 7;
#pragma unroll
      for (int it = 0; it < 2; ++it) {
        int mm = m + it * 32;
        int n = n0 + mm;
        int t = n & 1023;
        int tsrc = t + ksl - 2;
        float4 v = make_float4(0.f, 0.f, 0.f, 0.f);
        if ((unsigned)tsrc < 1024u)
          v = *(const float4*)&Hin[(size_t)(n + ksl - 2) * 256 + cin0 + k4 * 4];
        *(float4*)&As[mm][k4 * 4] = v;
      }
    }
    {  // stage W: direct copy from pre-transposed Wt; cols = a-half then g-half
      int kq = tid >> 4;          // 0..15
      int c4 = tid & 15;
#pragma unroll
      for (int it = 0; it < 2; ++it) {
        int k = kq + it * 16;
        int col = (c4 < 8) ? (cg * 32 + c4 * 4) : (256 + cg * 32 + (c4 - 8) * 4);
        float4 v = *(const float4*)&Wt[(size_t)(kt * 32 + k) * 512 + col];
        *(float4*)&Ws[k][c4 * 4] = v;
      }
    }
    __syncthreads();
    tile_fma_(As, Ws, acc, tx, ty);
    __syncthreads();
  }
  // epilogue: y tile -> LDS so each thread can pair a-col with its g-col
#pragma unroll
  for (int i = 0; i < 4; ++i)
    *(float4*)&Yt[ty * 4 + i][tx * 4] =
        make_float4(acc[i][0], acc[i][1], acc[i][2], acc[i][3]);
  __syncthreads();
  int row = tid >> 2, cq = tid & 3;   // 64 rows x 8 cols per thread
  int n = n0 + row;
  int ca = cg * 32 + cq * 8;          // global a-channel base
  float4 ya0 = *(const float4*)&Yt[row][cq * 8];
  float4 ya1 = *(const float4*)&Yt[row][cq * 8 + 4];
  float4 yg0 = *(const float4*)&Yt[row][32 + cq * 8];
  float4 yg1 = *(const float4*)&Yt[row][32 + cq * 8 + 4];
  float4 ba0 = *(const float4*)&cb[ca];
  float4 ba1 = *(const float4*)&cb[ca + 4];
  float4 bg0 = *(const float4*)&cb[256 + ca];
  float4 bg1 = *(const float4*)&cb[256 + ca + 4];
  float4 r0 = *(const float4*)&Hin[(size_t)n * 256 + ca];
  float4 r1 = *(const float4*)&Hin[(size_t)n * 256 + ca + 4];
  float4 o0, o1;
  o0.x = r0.x + (ya0.x + ba0.x) * sigmoidf_(yg0.x + bg0.x);
  o0.y = r0.y + (ya0.y + ba0.y) * sigmoidf_(yg0.y + bg0.y);
  o0.z = r0.z + (ya0.z + ba0.z) * sigmoidf_(yg0.z + bg0.z);
  o0.w = r0.w + (ya0.w + ba0.w) * sigmoidf_(yg0.w + bg0.w);
  o1.x = r1.x + (ya1.x + ba1.x) * sigmoidf_(yg1.x + bg1.x);
  o1.y = r1.y + (ya1.y + ba1.y) * sigmoidf_(yg1.y + bg1.y);
  o1.z = r1.z + (ya1.z + ba1.z) * sigmoidf_(yg1.z + bg1.z);
  o1.w = r1.w + (ya1.w + ba1.w) * sigmoidf_(yg1.w + bg1.w);
  if (DO_MASK) {
    if (fmask[n] != 0.f) {
      o0 = make_float4(0.f, 0.f, 0.f, 0.f);
      o1 = make_float4(0.f, 0.f, 0.f, 0.f);
    }
  }
  *(float4*)&Hout[(size_t)n * 256 + ca] = o0;
  *(float4*)&Hout[(size_t)n * 256 + ca + 4] = o1;
}

// ---------------------------------------------------------------------------
// Flash-style attention, fp32. Q/K/V stored [N, 256] (col = h*128 + dk).
// Block: one (b,h), 32 query rows; loops 32-key tiles. Online softmax.
// Thread (tx,ty): S rows {ty, ty+16} x cols {tx, tx+16};
// O rows {ty,ty+16} x cols {tx*4..+3, 64+tx*4..+3} (bank-friendly mapping).
// ---------------------------------------------------------------------------
__global__ __launch_bounds__(256) void attn_kernel(
    const float* __restrict__ Q, const float* __restrict__ K,
    const float* __restrict__ V, const float* __restrict__ fmask,
    float* __restrict__ O) {
  __shared__ __align__(16) float Qt[32][132];
  __shared__ __align__(16) float Kt[32][132];
  __shared__ __align__(16) float Vt[32][132];
  __shared__ __align__(16) float Pt[32][33];
  __shared__ float kmask[32];
  int tid = threadIdx.x;
  int tx = tid & 15, ty = tid >> 4;
  int q0 = blockIdx.x * 32;
  int bh = blockIdx.y;
  int b = bh >> 1, h = bh & 1;
  size_t base = (size_t)b * 1024 * 256 + (size_t)h * 128;
#pragma unroll
  for (int i = 0; i < 4; ++i) {
    int e = tid + i * 256;
    int r = e >> 5, d4 = e & 31;
    *(float4*)&Qt[r][d4 * 4] =
        *(const float4*)&Q[base + (size_t)(q0 + r) * 256 + d4 * 4];
  }
  float o[2][8] = {};
  float mi[2] = {-1e30f, -1e30f};
  float li[2] = {0.f, 0.f};
  for (int kt = 0; kt < 32; ++kt) {
    int k0 = kt * 32;
    __syncthreads();  // protect Kt/Vt/Pt from previous iteration's readers
#pragma unroll
    for (int i = 0; i < 4; ++i) {
      int e = tid + i * 256;
      int r = e >> 5, d4 = e & 31;
      *(float4*)&Kt[r][d4 * 4] =
          *(const float4*)&K[base + (size_t)(k0 + r) * 256 + d4 * 4];
      *(float4*)&Vt[r][d4 * 4] =
          *(const float4*)&V[base + (size_t)(k0 + r) * 256 + d4 * 4];
    }
    if (tid < 32) kmask[tid] = fmask[b * 1024 + k0 + tid];
    __syncthreads();
    float s00 = 0.f, s01 = 0.f, s10 = 0.f, s11 = 0.f;
#pragma unroll 8
    for (int d4 = 0; d4 < 32; ++d4) {
      float4 qa = *(const float4*)&Qt[ty][d4 * 4];
      float4 qb = *(const float4*)&Qt[ty + 16][d4 * 4];
      float4 ka = *(const float4*)&Kt[tx][d4 * 4];
      float4 kb = *(const float4*)&Kt[tx + 16][d4 * 4];
      s00 += qa.x * ka.x + qa.y * ka.y + qa.z * ka.z + qa.w * ka.w;
      s01 += qa.x * kb.x + qa.y * kb.y + qa.z * kb.z + qa.w * kb.w;
      s10 += qb.x * ka.x + qb.y * ka.y + qb.z * ka.z + qb.w * ka.w;
      s11 += qb.x * kb.x + qb.y * kb.y + qb.z * kb.z + qb.w * kb.w;
    }
    float km0 = kmask[tx], km1 = kmask[tx + 16];
    s00 = (km0 != 0.f) ? -1e30f : s00 * 0.0625f;   // TEMP = sqrt(256) = 16
    s10 = (km0 != 0.f) ? -1e30f : s10 * 0.0625f;
    s01 = (km1 != 0.f) ? -1e30f : s01 * 0.0625f;
    s11 = (km1 != 0.f) ? -1e30f : s11 * 0.0625f;
    float mt0 = fmaxf(s00, s01), mt1 = fmaxf(s10, s11);
#pragma unroll
    for (int off = 1; off < 16; off <<= 1) {
      mt0 = fmaxf(mt0, __shfl_xor(mt0, off, 64));
      mt1 = fmaxf(mt1, __shfl_xor(mt1, off, 64));
    }
    float scale0, scale1, p00, p01, p10, p11;
    {
      float mnew = fmaxf(mi[0], mt0);
      scale0 = __expf(mi[0] - mnew);
      bool dead = (mnew <= -1e29f);  // whole row masked so far
      p00 = dead ? 0.f : __expf(s00 - mnew);
      p01 = dead ? 0.f : __expf(s01 - mnew);
      mi[0] = mnew;
    }
    {
      float mnew = fmaxf(mi[1], mt1);
      scale1 = __expf(mi[1] - mnew);
      bool dead = (mnew <= -1e29f);
      p10 = dead ? 0.f : __expf(s10 - mnew);
      p11 = dead ? 0.f : __expf(s11 - mnew);
      mi[1] = mnew;
    }
    float rs0 = p00 + p01, rs1 = p10 + p11;
#pragma unroll
    for (int off = 1; off < 16; off <<= 1) {
      rs0 += __shfl_xor(rs0, off, 64);
      rs1 += __shfl_xor(rs1, off, 64);
    }
    li[0] = li[0] * scale0 + rs0;
    li[1] = li[1] * scale1 + rs1;
    Pt[ty][tx] = p00; Pt[ty][tx + 16] = p01;
    Pt[ty + 16][tx] = p10; Pt[ty + 16][tx + 16] = p11;
    __syncthreads();
#pragma unroll
    for (int c = 0; c < 8; ++c) { o[0][c] *= scale0; o[1][c] *= scale1; }
#pragma unroll 4
    for (int kk = 0; kk < 32; ++kk) {
      float p0 = Pt[ty][kk], p1 = Pt[ty + 16][kk];
      float4 va = *(const float4*)&Vt[kk][tx * 4];
      float4 vb = *(const float4*)&Vt[kk][64 + tx * 4];
      o[0][0] += p0 * va.x; o[0][1] += p0 * va.y; o[0][2] += p0 * va.z; o[0][3] += p0 * va.w;
      o[0][4] += p0 * vb.x; o[0][5] += p0 * vb.y; o[0][6] += p0 * vb.z; o[0][7] += p0 * vb.w;
      o[1][0] += p1 * va.x; o[1][1] += p1 * va.y; o[1][2] += p1 * va.z; o[1][3] += p1 * va.w;
      o[1][4] += p1 * vb.x; o[1][5] += p1 * vb.y; o[1][6] += p1 * vb.z; o[1][7] += p1 * vb.w;
    }
  }
#pragma unroll
  for (int i = 0; i < 2; ++i) {
    float inv = (li[i] > 0.f) ? 1.f / li[i] : 0.f;
    int r = q0 + ty + i * 16;
    float4 o0 = make_float4(o[i][0] * inv, o[i][1] * inv, o[i][2] * inv, o[i][3] * inv);
    float4 o1 = make_float4(o[i][4] * inv, o[i][5] * inv, o[i][6] * inv, o[i][7] * inv);
    *(float4*)&O[base + (size_t)r * 256 + tx * 4] = o0;
    *(float4*)&O[base + (size_t)r * 256 + 64 + tx * 4] = o1;
  }
}

// ---------------------------------------------------------------------------
// Pool prep: zero pooled accumulator, compute len[b] = #unmasked frames.
// ---------------------------------------------------------------------------
__global__ __launch_bounds__(256) void pool_prep_kernel(
    const float* __restrict__ fmask, float* __restrict__ pooled,
    float* __restrict__ lenb) {
  int b = blockIdx.x, tid = threadIdx.x;
  pooled[b * 256 + tid] = 0.f;
  float c = 0.f;
  for (int i = 0; i < 4; ++i)
    c += (fmask[b * 1024 + i * 256 + tid] == 0.f) ? 1.f : 0.f;
  __shared__ float red[256];
  red[tid] = c;
  __syncthreads();
  for (int s = 128; s > 0; s >>= 1) {
    if (tid < s) red[tid] += red[tid + s];
    __syncthreads();
  }
  if (tid == 0) lenb[b] = red[0];
}

// pooled[b][d] += sum over unmasked t of h5[b,t,d]
__global__ __launch_bounds__(256) void pool_kernel(
    const float* __restrict__ h5, const float* __restrict__ fmask,
    float* __restrict__ pooled) {
  int ch = blockIdx.x, b = blockIdx.y, d = threadIdx.x;
  float s = 0.f;
  for (int i = 0; i < 32; ++i) {
    int t = ch * 32 + i;
    if (fmask[b * 1024 + t] == 0.f)
      s += h5[((size_t)b * 1024 + t) * 256 + d];
  }
  atomicAdd(&pooled[b * 256 + d], s);
}

// out[b][j] = dot(pooled[b,:], Wf[j,:]) / len[b] + bf[j]
__global__ __launch_bounds__(256) void final_kernel(
    const float* __restrict__ pooled, const float* __restrict__ lenb,
    const float* __restrict__ Wf, const float* __restrict__ bf,
    float* __restrict__ out) {
  int b = blockIdx.x, j = threadIdx.x;
  __shared__ __align__(16) float p[256];
  p[j] = pooled[b * 256 + j];
  __syncthreads();
  const float* w = Wf + (size_t)j * 256;
  float s = 0.f;
  for (int d4 = 0; d4 < 64; ++d4) {
    float4 wv = ((const float4*)w)[d4];
    float4 pv = ((const float4*)p)[d4];
    s += wv.x * pv.x + wv.y * pv.y + wv.z * pv.z + wv.w * pv.w;
  }
  float len = lenb[b];
  float inv = (len > 0.f) ? 1.f / len : 0.f;
  out[b * 256 + j] = s * inv + bf[j];
}

// ---------------------------------------------------------------------------
extern "C" void kernel_launch(void* const* d_in, const int* in_sizes, int n_in,
                              void* d_out, int out_size, void* d_ws, size_t ws_size,
                              hipStream_t stream) {
  const float* x      = (const float*)d_in[0];
  const unsigned* msk = (const unsigned*)d_in[1];
  const float* W1 = (const float*)d_in[2];
  const float* b1 = (const float*)d_in[3];
  const float* W2 = (const float*)d_in[4];
  const float* b2 = (const float*)d_in[5];
  const float* cW1 = (const float*)d_in[6];
  const float* cb1 = (const float*)d_in[7];
  const float* cW2 = (const float*)d_in[8];
  const float* cb2 = (const float*)d_in[9];
  const float* Wq = (const float*)d_in[10];
  const float* bq = (const float*)d_in[11];
  const float* Wk = (const float*)d_in[12];
  const float* bk = (const float*)d_in[13];
  const float* Wv = (const float*)d_in[14];
  const float* bv = (const float*)d_in[15];
  const float* Wo = (const float*)d_in[16];
  const float* bo = (const float*)d_in[17];
  const float* Wf = (const float*)d_in[18];
  const float* bf = (const float*)d_in[19];
  float* out = (float*)d_out;

  // workspace layout (fp32), ~106 MB total
  float* ws = (float*)d_ws;
  size_t ND = (size_t)N_ * D_;
  float* bufA  = ws;             // h1 / h3 / h5
  float* bufB  = bufA + ND;      // h2 / masked-h (residual)
  float* Qb    = bufB + ND;
  float* Kb    = Qb + ND;
  float* Vb    = Kb + ND;
  float* Ob    = Vb + ND;
  float* Wt1   = Ob + ND;        // [1280][512]
  float* Wt2   = Wt1 + (size_t)C2_ * KKC_;
  float* fmask = Wt2 + (size_t)C2_ * KKC_;   // [16384]
  float* pooled = fmask + N_;                // [16*256]
  float* lenb   = pooled + B_ * D_;          // [16]

  dim3 blk(256);
  mask_prep_kernel<<<dim3(64), blk, 0, stream>>>(msk, fmask);
  transpose_w_kernel<<<dim3((C2_ * KKC_ + 255) / 256), blk, 0, stream>>>(cW1, Wt1);
  transpose_w_kernel<<<dim3((C2_ * KKC_ + 255) / 256), blk, 0, stream>>>(cW2, Wt2);
  // spectral MLP
  gemm_kernel<1, 0><<<dim3(4, 256), blk, 0, stream>>>(x, W1, b1, nullptr, bufA, N_, D_, D_);
  gemm_kernel<1, 0><<<dim3(4, 256), blk, 0, stream>>>(bufA, W2, b2, nullptr, bufB, N_, D_, D_);
  // temporal Conv1dGLU x2 (second fuses the mask-zeroing)
  conv_glu_kernel<0><<<dim3(8, 256), blk, 0, stream>>>(bufB, Wt1, cb1, fmask, bufA);
  conv_glu_kernel<1><<<dim3(8, 256), blk, 0, stream>>>(bufA, Wt2, cb2, fmask, bufB);
  // attention
  gemm_kernel<0, 0><<<dim3(4, 256), blk, 0, stream>>>(bufB, Wq, bq, nullptr, Qb, N_, D_, D_);
  gemm_kernel<0, 0><<<dim3(4, 256), blk, 0, stream>>>(bufB, Wk, bk, nullptr, Kb, N_, D_, D_);
  gemm_kernel<0, 0><<<dim3(4, 256), blk, 0, stream>>>(bufB, Wv, bv, nullptr, Vb, N_, D_, D_);
  attn_kernel<<<dim3(32, 32), blk, 0, stream>>>(Qb, Kb, Vb, fmask, Ob);
  gemm_kernel<0, 1><<<dim3(4, 256), blk, 0, stream>>>(Ob, Wo, bo, bufB, bufA, N_, D_, D_);
  // fused final: pool unmasked h5 first, then one tiny [16x256]x[256x256] proj
  pool_prep_kernel<<<dim3(16), blk, 0, stream>>>(fmask, pooled, lenb);
  pool_kernel<<<dim3(32, 16), blk, 0, stream>>>(bufA, fmask, pooled);
  final_kernel<<<dim3(16), blk, 0, stream>>>(pooled, lenb, Wf, bf, out);
}

// Round 2
// 1096.042 us; speedup vs baseline: 1.2410x; 1.2410x over previous
//
#include <hip/hip_runtime.h>
#include <hip/hip_bf16.h>
#include <math.h>

// ============================================================================
// StylePredictor: spectral MLP (mish) -> 2x Conv1dGLU -> mask -> MHSA ->
// out-proj + residual -> fused (pool-then-project) final layer.
// Round 2: attention -> bf16 MFMA flash attention; QKV GEMMs emit bf16.
// ============================================================================

#define DEV __device__ __forceinline__

static constexpr int B_ = 16, T_ = 1024, D_ = 256;
static constexpr int N_ = B_ * T_;           // 16384 rows
static constexpr int C2_ = 2 * D_;           // 512 conv out channels
static constexpr int KW_ = 5;
static constexpr int KKC_ = D_ * KW_;        // 1280 implicit-GEMM K

typedef __attribute__((ext_vector_type(8))) short bf16x8;
typedef __attribute__((ext_vector_type(4))) float floatx4;

DEV float sigmoidf_(float x) { return 1.f / (1.f + __expf(-x)); }
DEV float mishf_(float x) {
  float sp = (x > 20.f) ? x : log1pf(expf(x));
  return x * tanhf(sp);
}
DEV ushort f2bf_(float x) {
  __hip_bfloat16 h = __float2bfloat16(x);
  return *(ushort*)&h;
}

// ---------------------------------------------------------------------------
// Mask prep: detect storage layout of the bool mask (int32 / int8 / float32)
// and write fp32 fmask (1.0 = masked/zeroed, 0.0 = keep).
// ---------------------------------------------------------------------------
__global__ __launch_bounds__(256) void mask_prep_kernel(
    const unsigned* __restrict__ mraw, float* __restrict__ fmask) {
  int tid = threadIdx.x;
  int isByte = 0, isFloat = 0;
  for (int i = 0; i < 16; ++i) {
    unsigned v = mraw[tid * 16 + i];
    if (v == 0x3F800000u) isFloat = 1;
    else if (v > 1u) isByte = 1;
  }
  __shared__ int sByte, sFloat;
  if (tid == 0) { sByte = 0; sFloat = 0; }
  __syncthreads();
  if (isByte) atomicOr(&sByte, 1);
  if (isFloat) atomicOr(&sFloat, 1);
  __syncthreads();
  int mode = sFloat ? 2 : (sByte ? 1 : 0);
  int idx = blockIdx.x * 256 + tid;
  unsigned mv;
  if (mode == 1) mv = ((const unsigned char*)mraw)[idx];
  else           mv = mraw[idx];
  fmask[idx] = (mv != 0u) ? 1.f : 0.f;
}

// ---------------------------------------------------------------------------
// Weight transpose for conv implicit GEMM:
//   wt[(k*256+cin)*512 + co] = cw[co*1280 + cin*5 + k]
// ---------------------------------------------------------------------------
__global__ __launch_bounds__(256) void transpose_w_kernel(
    const float* __restrict__ cw, float* __restrict__ wt) {
  int i = blockIdx.x * 256 + threadIdx.x;
  if (i >= C2_ * KKC_) return;
  int co = i / KKC_;
  int r = i - co * KKC_;
  int cin = r / KW_;
  int k = r - cin * KW_;
  wt[(size_t)(k * D_ + cin) * C2_ + co] = cw[i];
}

// ---------------------------------------------------------------------------
// Shared 64x64 fp32 tile FMA (used by gemm_kernel / conv_glu_kernel).
// ---------------------------------------------------------------------------
DEV void tile_fma_(const float (*As)[36], const float (*Ws)[68],
                   float acc[4][4], int tx, int ty) {
#pragma unroll
  for (int k4 = 0; k4 < 8; ++k4) {
    float4 b4[4];
#pragma unroll
    for (int kk = 0; kk < 4; ++kk)
      b4[kk] = *(const float4*)&Ws[k4 * 4 + kk][tx * 4];
#pragma unroll
    for (int i = 0; i < 4; ++i) {
      float4 a4 = *(const float4*)&As[ty * 4 + i][k4 * 4];
#pragma unroll
      for (int kk = 0; kk < 4; ++kk) {
        float av = (kk == 0) ? a4.x : (kk == 1) ? a4.y : (kk == 2) ? a4.z : a4.w;
        acc[i][0] += av * b4[kk].x;
        acc[i][1] += av * b4[kk].y;
        acc[i][2] += av * b4[kk].z;
        acc[i][3] += av * b4[kk].w;
      }
    }
  }
}

// ---------------------------------------------------------------------------
// Generic fp32 GEMM: C = act(A @ W^T + bias) [+ resid]
// OBF16: emit bf16 output (for attention Q/K/V).
// ---------------------------------------------------------------------------
template <int ACT, int RESID, int OBF16>
__global__ __launch_bounds__(256) void gemm_kernel(
    const float* __restrict__ A, const float* __restrict__ W,
    const float* __restrict__ bias, const float* __restrict__ resid,
    void* __restrict__ Cv, int Nrows, int Din, int Dout) {
  __shared__ __align__(16) float As[64][36];
  __shared__ __align__(16) float Ws[32][68];
  int tid = threadIdx.x;
  int tx = tid & 15, ty = tid >> 4;
  int c0 = blockIdx.x * 64;
  int n0 = blockIdx.y * 64;
  float acc[4][4] = {};
  int nkt = Din >> 5;
  for (int kt = 0; kt < nkt; ++kt) {
    int k0 = kt << 5;
    {  // stage A
      int m = tid >> 3, k4 = tid & 7;
      *(float4*)&As[m][k4 * 4] =
          *(const float4*)&A[(size_t)(n0 + m) * Din + k0 + k4 * 4];
      *(float4*)&As[m + 32][k4 * 4] =
          *(const float4*)&A[(size_t)(n0 + m + 32) * Din + k0 + k4 * 4];
    }
    {  // stage W transposed
      int n = tid >> 3, k4 = tid & 7;
      float4 w0 = *(const float4*)&W[(size_t)(c0 + n) * Din + k0 + k4 * 4];
      Ws[k4 * 4 + 0][n] = w0.x; Ws[k4 * 4 + 1][n] = w0.y;
      Ws[k4 * 4 + 2][n] = w0.z; Ws[k4 * 4 + 3][n] = w0.w;
      float4 w1 = *(const float4*)&W[(size_t)(c0 + n + 32) * Din + k0 + k4 * 4];
      Ws[k4 * 4 + 0][n + 32] = w1.x; Ws[k4 * 4 + 1][n + 32] = w1.y;
      Ws[k4 * 4 + 2][n + 32] = w1.z; Ws[k4 * 4 + 3][n + 32] = w1.w;
    }
    __syncthreads();
    tile_fma_(As, Ws, acc, tx, ty);
    __syncthreads();
  }
  float4 bv = *(const float4*)&bias[c0 + tx * 4];
#pragma unroll
  for (int i = 0; i < 4; ++i) {
    int row = n0 + ty * 4 + i;
    float4 c;
    c.x = acc[i][0] + bv.x; c.y = acc[i][1] + bv.y;
    c.z = acc[i][2] + bv.z; c.w = acc[i][3] + bv.w;
    if (ACT == 1) { c.x = mishf_(c.x); c.y = mishf_(c.y); c.z = mishf_(c.z); c.w = mishf_(c.w); }
    if (RESID) {
      float4 r = *(const float4*)&resid[(size_t)row * Dout + c0 + tx * 4];
      c.x += r.x; c.y += r.y; c.z += r.z; c.w += r.w;
    }
    if (OBF16) {
      ushort4 u;
      u.x = f2bf_(c.x); u.y = f2bf_(c.y); u.z = f2bf_(c.z); u.w = f2bf_(c.w);
      *(ushort4*)&((ushort*)Cv)[(size_t)row * Dout + c0 + tx * 4] = u;
    } else {
      *(float4*)&((float*)Cv)[(size_t)row * Dout + c0 + tx * 4] = c;
    }
  }
}

// ---------------------------------------------------------------------------
// Conv1dGLU as implicit GEMM (fp32, unchanged this round).
// ---------------------------------------------------------------------------
template <int DO_MASK>
__global__ __launch_bounds__(256) void conv_glu_kernel(
    const float* __restrict__ Hin, const float* __restrict__ Wt,
    const float* __restrict__ cb, const float* __restrict__ fmask,
    float* __restrict__ Hout) {
  __shared__ __align__(16) float As[64][36];
  __shared__ __align__(16) float Ws[32][68];
  __shared__ __align__(16) float Yt[64][68];
  int tid = threadIdx.x;
  int tx = tid & 15, ty = tid >> 4;
  int cg = blockIdx.x;
  int n0 = blockIdx.y * 64;
  float acc[4][4] = {};
  for (int kt = 0; kt < 40; ++kt) {
    int ksl = kt >> 3;
    int cin0 = (kt & 7) << 5;
    {
      int m = tid >> 3, k4 = tid & 7;
#pragma unroll
      for (int it = 0; it < 2; ++it) {
        int mm = m + it * 32;
        int n = n0 + mm;
        int t = n & 1023;
        int tsrc = t + ksl - 2;
        float4 v = make_float4(0.f, 0.f, 0.f, 0.f);
        if ((unsigned)tsrc < 1024u)
          v = *(const float4*)&Hin[(size_t)(n + ksl - 2) * 256 + cin0 + k4 * 4];
        *(float4*)&As[mm][k4 * 4] = v;
      }
    }
    {
      int kq = tid >> 4;
      int c4 = tid & 15;
#pragma unroll
      for (int it = 0; it < 2; ++it) {
        int k = kq + it * 16;
        int col = (c4 < 8) ? (cg * 32 + c4 * 4) : (256 + cg * 32 + (c4 - 8) * 4);
        float4 v = *(const float4*)&Wt[(size_t)(kt * 32 + k) * 512 + col];
        *(float4*)&Ws[k][c4 * 4] = v;
      }
    }
    __syncthreads();
    tile_fma_(As, Ws, acc, tx, ty);
    __syncthreads();
  }
#pragma unroll
  for (int i = 0; i < 4; ++i)
    *(float4*)&Yt[ty * 4 + i][tx * 4] =
        make_float4(acc[i][0], acc[i][1], acc[i][2], acc[i][3]);
  __syncthreads();
  int row = tid >> 2, cq = tid & 3;
  int n = n0 + row;
  int ca = cg * 32 + cq * 8;
  float4 ya0 = *(const float4*)&Yt[row][cq * 8];
  float4 ya1 = *(const float4*)&Yt[row][cq * 8 + 4];
  float4 yg0 = *(const float4*)&Yt[row][32 + cq * 8];
  float4 yg1 = *(const float4*)&Yt[row][32 + cq * 8 + 4];
  float4 ba0 = *(const float4*)&cb[ca];
  float4 ba1 = *(const float4*)&cb[ca + 4];
  float4 bg0 = *(const float4*)&cb[256 + ca];
  float4 bg1 = *(const float4*)&cb[256 + ca + 4];
  float4 r0 = *(const float4*)&Hin[(size_t)n * 256 + ca];
  float4 r1 = *(const float4*)&Hin[(size_t)n * 256 + ca + 4];
  float4 o0, o1;
  o0.x = r0.x + (ya0.x + ba0.x) * sigmoidf_(yg0.x + bg0.x);
  o0.y = r0.y + (ya0.y + ba0.y) * sigmoidf_(yg0.y + bg0.y);
  o0.z = r0.z + (ya0.z + ba0.z) * sigmoidf_(yg0.z + bg0.z);
  o0.w = r0.w + (ya0.w + ba0.w) * sigmoidf_(yg0.w + bg0.w);
  o1.x = r1.x + (ya1.x + ba1.x) * sigmoidf_(yg1.x + bg1.x);
  o1.y = r1.y + (ya1.y + ba1.y) * sigmoidf_(yg1.y + bg1.y);
  o1.z = r1.z + (ya1.z + ba1.z) * sigmoidf_(yg1.z + bg1.z);
  o1.w = r1.w + (ya1.w + ba1.w) * sigmoidf_(yg1.w + bg1.w);
  if (DO_MASK) {
    if (fmask[n] != 0.f) {
      o0 = make_float4(0.f, 0.f, 0.f, 0.f);
      o1 = make_float4(0.f, 0.f, 0.f, 0.f);
    }
  }
  *(float4*)&Hout[(size_t)n * 256 + ca] = o0;
  *(float4*)&Hout[(size_t)n * 256 + ca + 4] = o1;
}

// ---------------------------------------------------------------------------
// bf16 MFMA flash attention. Q/K/V bf16 [N,256] (col = h*128 + dk), O fp32.
// Block = one (b,h) x 64 q-rows; wave w owns rows qw0..qw0+15 (Q frags in
// registers). K-loop over 32-key tiles:
//   S = Q.K^T via mfma_f32_16x16x32_bf16 (2 col-tiles x 4 k-chunks),
//   online softmax in C-layout regs (rows = quad*4+reg, quad-local shuffles),
//   P -> per-wave LDS (C-layout scatter, A-layout b128 gather),
//   O += P.V via 8 dv-tiles; V staged in frag-ordered LDS for b128 B-frags.
// Verified layouts: C/D col=lane&15,row=quad*4+reg; A/B [15&lane][quad*8+j].
// ---------------------------------------------------------------------------
__global__ __launch_bounds__(256) void attn_mfma_kernel(
    const ushort* __restrict__ Q, const ushort* __restrict__ K,
    const ushort* __restrict__ V, const float* __restrict__ fmask,
    float* __restrict__ O) {
  __shared__ ushort Kt[32][136];       // [kt][dk], b128-aligned rows
  __shared__ ushort Vf[4096];          // frag-ordered: ((dv>>4)*4+(kt>>3))*16+(dv&15))*8+(kt&7)
  __shared__ ushort Pw[4][16][40];     // per-wave P [q][kt]
  __shared__ float kmask[32];
  int tid = threadIdx.x;
  int w = tid >> 6, lane = tid & 63;
  int quad = lane >> 4, l16 = lane & 15;
  int b = blockIdx.y >> 1, h = blockIdx.y & 1;
  int qw0 = blockIdx.x * 64 + w * 16;
  size_t rowQ = (size_t)(b * 1024 + qw0 + l16) * 256 + h * 128;
  bf16x8 qf[4];
#pragma unroll
  for (int c = 0; c < 4; ++c)
    qf[c] = *(const bf16x8*)&Q[rowQ + c * 32 + quad * 8];
  floatx4 oacc[8];
#pragma unroll
  for (int n = 0; n < 8; ++n) oacc[n] = (floatx4){0.f, 0.f, 0.f, 0.f};
  float mi[4] = {-1e30f, -1e30f, -1e30f, -1e30f};
  float li[4] = {0.f, 0.f, 0.f, 0.f};
  size_t kvbase = (size_t)(b * 1024) * 256 + h * 128;
  for (int kt0 = 0; kt0 < 1024; kt0 += 32) {
    __syncthreads();  // protect Kt/Vf from previous iteration's readers
#pragma unroll
    for (int r = 0; r < 2; ++r) {
      int cid = tid + r * 256;
      int row = cid >> 4, off8 = (cid & 15) * 8;   // kt-local row, dk chunk
      *(uint4*)&Kt[row][off8] =
          *(const uint4*)&K[kvbase + (size_t)(kt0 + row) * 256 + off8];
      uint4 vv = *(const uint4*)&V[kvbase + (size_t)(kt0 + row) * 256 + off8];
      const ushort* pv = (const ushort*)&vv;
      int qp = row >> 3, j = row & 7;
#pragma unroll
      for (int i = 0; i < 8; ++i) {
        int dv = off8 + i;
        Vf[(((dv >> 4) * 4 + qp) * 16 + (dv & 15)) * 8 + j] = pv[i];
      }
    }
    if (tid < 32) kmask[tid] = fmask[b * 1024 + kt0 + tid];
    __syncthreads();
    // S = Q.K^T  (two 16-col tiles)
    floatx4 sa0 = {0.f, 0.f, 0.f, 0.f}, sa1 = {0.f, 0.f, 0.f, 0.f};
#pragma unroll
    for (int c = 0; c < 4; ++c) {
      bf16x8 k0f = *(const bf16x8*)&Kt[l16][c * 32 + quad * 8];
      bf16x8 k1f = *(const bf16x8*)&Kt[16 + l16][c * 32 + quad * 8];
      sa0 = __builtin_amdgcn_mfma_f32_16x16x32_bf16(qf[c], k0f, sa0, 0, 0, 0);
      sa1 = __builtin_amdgcn_mfma_f32_16x16x32_bf16(qf[c], k1f, sa1, 0, 0, 0);
    }
    float km0 = kmask[l16], km1 = kmask[16 + l16];
    float alpha[4];
#pragma unroll
    for (int r = 0; r < 4; ++r) {
      float s0 = (km0 != 0.f) ? -1e30f : sa0[r] * 0.0625f;  // TEMP = 16
      float s1 = (km1 != 0.f) ? -1e30f : sa1[r] * 0.0625f;
      float mt = fmaxf(s0, s1);
      mt = fmaxf(mt, __shfl_xor(mt, 1));
      mt = fmaxf(mt, __shfl_xor(mt, 2));
      mt = fmaxf(mt, __shfl_xor(mt, 4));
      mt = fmaxf(mt, __shfl_xor(mt, 8));
      float mnew = fmaxf(mi[r], mt);
      alpha[r] = __expf(mi[r] - mnew);
      bool dead = (mnew <= -1e29f);   // whole row masked so far
      float p0 = dead ? 0.f : __expf(s0 - mnew);
      float p1 = dead ? 0.f : __expf(s1 - mnew);
      float rs = p0 + p1;
      rs += __shfl_xor(rs, 1);
      rs += __shfl_xor(rs, 2);
      rs += __shfl_xor(rs, 4);
      rs += __shfl_xor(rs, 8);
      li[r] = li[r] * alpha[r] + rs;
      mi[r] = mnew;
      Pw[w][quad * 4 + r][l16] = f2bf_(p0);
      Pw[w][quad * 4 + r][16 + l16] = f2bf_(p1);
    }
    __syncthreads();  // Pw cross-lane visibility (also paces the loop)
    bf16x8 pf = *(const bf16x8*)&Pw[w][l16][quad * 8];
#pragma unroll
    for (int n = 0; n < 8; ++n) {
      floatx4 o = oacc[n];
      o[0] *= alpha[0]; o[1] *= alpha[1]; o[2] *= alpha[2]; o[3] *= alpha[3];
      bf16x8 vf = *(const bf16x8*)&Vf[((n * 4 + quad) * 16 + l16) * 8];
      oacc[n] = __builtin_amdgcn_mfma_f32_16x16x32_bf16(pf, vf, o, 0, 0, 0);
    }
  }
  float inv[4];
#pragma unroll
  for (int r = 0; r < 4; ++r) inv[r] = (li[r] > 0.f) ? 1.f / li[r] : 0.f;
#pragma unroll
  for (int n = 0; n < 8; ++n) {
#pragma unroll
    for (int r = 0; r < 4; ++r)
      O[kvbase + (size_t)(qw0 + quad * 4 + r) * 256 + n * 16 + l16] =
          oacc[n][r] * inv[r];
  }
}

// ---------------------------------------------------------------------------
// Pool prep: zero pooled accumulator, compute len[b] = #unmasked frames.
// ---------------------------------------------------------------------------
__global__ __launch_bounds__(256) void pool_prep_kernel(
    const float* __restrict__ fmask, float* __restrict__ pooled,
    float* __restrict__ lenb) {
  int b = blockIdx.x, tid = threadIdx.x;
  pooled[b * 256 + tid] = 0.f;
  float c = 0.f;
  for (int i = 0; i < 4; ++i)
    c += (fmask[b * 1024 + i * 256 + tid] == 0.f) ? 1.f : 0.f;
  __shared__ float red[256];
  red[tid] = c;
  __syncthreads();
  for (int s = 128; s > 0; s >>= 1) {
    if (tid < s) red[tid] += red[tid + s];
    __syncthreads();
  }
  if (tid == 0) lenb[b] = red[0];
}

__global__ __launch_bounds__(256) void pool_kernel(
    const float* __restrict__ h5, const float* __restrict__ fmask,
    float* __restrict__ pooled) {
  int ch = blockIdx.x, b = blockIdx.y, d = threadIdx.x;
  float s = 0.f;
  for (int i = 0; i < 32; ++i) {
    int t = ch * 32 + i;
    if (fmask[b * 1024 + t] == 0.f)
      s += h5[((size_t)b * 1024 + t) * 256 + d];
  }
  atomicAdd(&pooled[b * 256 + d], s);
}

__global__ __launch_bounds__(256) void final_kernel(
    const float* __restrict__ pooled, const float* __restrict__ lenb,
    const float* __restrict__ Wf, const float* __restrict__ bf,
    float* __restrict__ out) {
  int b = blockIdx.x, j = threadIdx.x;
  __shared__ __align__(16) float p[256];
  p[j] = pooled[b * 256 + j];
  __syncthreads();
  const float* w = Wf + (size_t)j * 256;
  float s = 0.f;
  for (int d4 = 0; d4 < 64; ++d4) {
    float4 wv = ((const float4*)w)[d4];
    float4 pv = ((const float4*)p)[d4];
    s += wv.x * pv.x + wv.y * pv.y + wv.z * pv.z + wv.w * pv.w;
  }
  float len = lenb[b];
  float inv = (len > 0.f) ? 1.f / len : 0.f;
  out[b * 256 + j] = s * inv + bf[j];
}

// ---------------------------------------------------------------------------
extern "C" void kernel_launch(void* const* d_in, const int* in_sizes, int n_in,
                              void* d_out, int out_size, void* d_ws, size_t ws_size,
                              hipStream_t stream) {
  const float* x      = (const float*)d_in[0];
  const unsigned* msk = (const unsigned*)d_in[1];
  const float* W1 = (const float*)d_in[2];
  const float* b1 = (const float*)d_in[3];
  const float* W2 = (const float*)d_in[4];
  const float* b2 = (const float*)d_in[5];
  const float* cW1 = (const float*)d_in[6];
  const float* cb1 = (const float*)d_in[7];
  const float* cW2 = (const float*)d_in[8];
  const float* cb2 = (const float*)d_in[9];
  const float* Wq = (const float*)d_in[10];
  const float* bq = (const float*)d_in[11];
  const float* Wk = (const float*)d_in[12];
  const float* bk = (const float*)d_in[13];
  const float* Wv = (const float*)d_in[14];
  const float* bv = (const float*)d_in[15];
  const float* Wo = (const float*)d_in[16];
  const float* bo = (const float*)d_in[17];
  const float* Wf = (const float*)d_in[18];
  const float* bf = (const float*)d_in[19];
  float* out = (float*)d_out;

  float* ws = (float*)d_ws;
  size_t ND = (size_t)N_ * D_;
  float* bufA  = ws;             // h1 / h3 / h5
  float* bufB  = bufA + ND;      // h2 / masked-h (residual)
  float* Qs    = bufB + ND;      // bf16 Q (uses half the slot)
  float* Ks    = Qs + ND;
  float* Vs    = Ks + ND;
  float* Ob    = Vs + ND;        // fp32 attention output
  float* Wt1   = Ob + ND;
  float* Wt2   = Wt1 + (size_t)C2_ * KKC_;
  float* fmask = Wt2 + (size_t)C2_ * KKC_;
  float* pooled = fmask + N_;
  float* lenb   = pooled + B_ * D_;
  ushort* Qb16 = (ushort*)Qs;
  ushort* Kb16 = (ushort*)Ks;
  ushort* Vb16 = (ushort*)Vs;

  dim3 blk(256);
  mask_prep_kernel<<<dim3(64), blk, 0, stream>>>(msk, fmask);
  transpose_w_kernel<<<dim3((C2_ * KKC_ + 255) / 256), blk, 0, stream>>>(cW1, Wt1);
  transpose_w_kernel<<<dim3((C2_ * KKC_ + 255) / 256), blk, 0, stream>>>(cW2, Wt2);
  // spectral MLP
  gemm_kernel<1, 0, 0><<<dim3(4, 256), blk, 0, stream>>>(x, W1, b1, nullptr, bufA, N_, D_, D_);
  gemm_kernel<1, 0, 0><<<dim3(4, 256), blk, 0, stream>>>(bufA, W2, b2, nullptr, bufB, N_, D_, D_);
  // temporal Conv1dGLU x2 (second fuses mask-zeroing)
  conv_glu_kernel<0><<<dim3(8, 256), blk, 0, stream>>>(bufB, Wt1, cb1, fmask, bufA);
  conv_glu_kernel<1><<<dim3(8, 256), blk, 0, stream>>>(bufA, Wt2, cb2, fmask, bufB);
  // attention: QKV projections emit bf16, MFMA flash attention, fp32 out
  gemm_kernel<0, 0, 1><<<dim3(4, 256), blk, 0, stream>>>(bufB, Wq, bq, nullptr, Qb16, N_, D_, D_);
  gemm_kernel<0, 0, 1><<<dim3(4, 256), blk, 0, stream>>>(bufB, Wk, bk, nullptr, Kb16, N_, D_, D_);
  gemm_kernel<0, 0, 1><<<dim3(4, 256), blk, 0, stream>>>(bufB, Wv, bv, nullptr, Vb16, N_, D_, D_);
  attn_mfma_kernel<<<dim3(16, 32), blk, 0, stream>>>(Qb16, Kb16, Vb16, fmask, Ob);
  gemm_kernel<0, 1, 0><<<dim3(4, 256), blk, 0, stream>>>(Ob, Wo, bo, bufB, bufA, N_, D_, D_);
  // fused final: pool unmasked h5 first, then tiny projection
  pool_prep_kernel<<<dim3(16), blk, 0, stream>>>(fmask, pooled, lenb);
  pool_kernel<<<dim3(32, 16), blk, 0, stream>>>(bufA, fmask, pooled);
  final_kernel<<<dim3(16), blk, 0, stream>>>(pooled, lenb, Wf, bf, out);
}

// Round 3
// 502.594 us; speedup vs baseline: 2.7062x; 2.1808x over previous
//
#include <hip/hip_runtime.h>
#include <hip/hip_bf16.h>
#include <math.h>

// ============================================================================
// StylePredictor. Round 3: conv + all dense GEMMs -> bf16 MFMA (32x32x16).
// Residual/epilogue arithmetic kept fp32; bf16 only on MFMA operands.
// ============================================================================

#define DEV __device__ __forceinline__

static constexpr int B_ = 16, T_ = 1024, D_ = 256;
static constexpr int N_ = B_ * T_;

typedef __attribute__((ext_vector_type(8))) short bf16x8;
typedef __attribute__((ext_vector_type(4))) float floatx4;
typedef __attribute__((ext_vector_type(16))) float floatx16;

DEV float sigmoidf_(float x) { return 1.f / (1.f + __expf(-x)); }
DEV float mishf_(float x) {
  float sp = (x > 20.f) ? x : log1pf(expf(x));
  return x * tanhf(sp);
}
DEV ushort f2bf_(float x) {
  __hip_bfloat16 h = __float2bfloat16(x);
  return *(ushort*)&h;
}
DEV float bf2f_(ushort u) {
  unsigned v = ((unsigned)u) << 16;
  return *(float*)&v;
}

// ---------------------------------------------------------------------------
// Mask prep: detect bool storage (int32 / int8 / fp32), emit fp32 fmask
// (1.0 = masked -> zero the frame).
// ---------------------------------------------------------------------------
__global__ __launch_bounds__(256) void mask_prep_kernel(
    const unsigned* __restrict__ mraw, float* __restrict__ fmask) {
  int tid = threadIdx.x;
  int isByte = 0, isFloat = 0;
  for (int i = 0; i < 16; ++i) {
    unsigned v = mraw[tid * 16 + i];
    if (v == 0x3F800000u) isFloat = 1;
    else if (v > 1u) isByte = 1;
  }
  __shared__ int sByte, sFloat;
  if (tid == 0) { sByte = 0; sFloat = 0; }
  __syncthreads();
  if (isByte) atomicOr(&sByte, 1);
  if (isFloat) atomicOr(&sFloat, 1);
  __syncthreads();
  int mode = sFloat ? 2 : (sByte ? 1 : 0);
  int idx = blockIdx.x * 256 + tid;
  unsigned mv;
  if (mode == 1) mv = ((const unsigned char*)mraw)[idx];
  else           mv = mraw[idx];
  fmask[idx] = (mv != 0u) ? 1.f : 0.f;
}

// ---------------------------------------------------------------------------
// fp32 -> bf16 bulk cast (float4 granules).
// ---------------------------------------------------------------------------
__global__ __launch_bounds__(256) void cast_f2b_kernel(
    const float* __restrict__ src, ushort* __restrict__ dst, int n4) {
  int i = blockIdx.x * 256 + threadIdx.x;
  if (i >= n4) return;
  float4 v = ((const float4*)src)[i];
  ushort4 u;
  u.x = f2bf_(v.x); u.y = f2bf_(v.y); u.z = f2bf_(v.z); u.w = f2bf_(v.w);
  ((ushort4*)dst)[i] = u;
}

// ---------------------------------------------------------------------------
// Conv weight prep: wtT[co*1280 + k*256 + cin] = bf16(cw[(co*256+cin)*5 + k])
// -> B-frag loads are contiguous in the implicit-GEMM K index (tap*256+cin).
// ---------------------------------------------------------------------------
__global__ __launch_bounds__(256) void conv_w_prep_kernel(
    const float* __restrict__ cw, ushort* __restrict__ wtT) {
  int i = blockIdx.x * 256 + threadIdx.x;
  if (i >= 512 * 1280) return;
  int co = i / 1280;
  int r = i - co * 1280;
  int k = r >> 8;
  int cin = r & 255;
  wtT[i] = f2bf_(cw[(size_t)(co * 256 + cin) * 5 + k]);
}

// ---------------------------------------------------------------------------
// bf16 MFMA GEMM: C = act(A @ W^T + bias) [+resid].  A16 [16384,256] bf16,
// W16 [256,256] bf16 (torch layout: row = out channel, contiguous in k).
// Block = 64 rows x 256 cols (full N), 4 waves; wave = 64 rows x 64 cols,
// 2x2 tiles of 32x32. A via LDS (72B stride, b64 pairs: 2-way = free);
// B-frags direct from global (k-contiguous, L1/L2 resident). A dbuf + B
// one-chunk-ahead register prefetch.
// 32x32x16 layouts: A/B [m|n=lane&31][k=(lane>>5)*8+j];
// C/D col=lane&31, row=(reg&3)+8*(reg>>2)+4*(lane>>5).
// ---------------------------------------------------------------------------
template <int ACT, int RESID, int OUTF32, int OUTB16>
__global__ __launch_bounds__(256, 2) void gemm_mfma_kernel(
    const ushort* __restrict__ A16, const ushort* __restrict__ W16,
    const float* __restrict__ bias, const float* __restrict__ resid,
    float* __restrict__ outf, ushort* __restrict__ outb) {
  __shared__ ushort As[2][64 * 36];
  int tid = threadIdx.x;
  int w = tid >> 6, lane = tid & 63;
  int m31 = lane & 31, half = lane >> 5;
  int n0 = blockIdx.x * 64;

  floatx16 acc[2][2];
#pragma unroll
  for (int a = 0; a < 2; ++a)
#pragma unroll
    for (int b = 0; b < 2; ++b)
#pragma unroll
      for (int i = 0; i < 16; ++i) acc[a][b][i] = 0.f;

  // stage A chunk 0
#pragma unroll
  for (int it = 0; it < 2; ++it) {
    int i = tid + it * 256;
    int row = i >> 3, part = i & 7;
    *(uint2*)&As[0][row * 36 + part * 4] =
        *(const uint2*)&A16[(size_t)(n0 + row) * 256 + part * 4];
  }
  // prefetch B chunk 0
  bf16x8 bn[2][2];
#pragma unroll
  for (int ks = 0; ks < 2; ++ks)
#pragma unroll
    for (int ct = 0; ct < 2; ++ct)
      bn[ks][ct] = *(const bf16x8*)&W16[(size_t)(w * 64 + ct * 32 + m31) * 256 +
                                        ks * 16 + half * 8];

  for (int c = 0; c < 8; ++c) {
    __syncthreads();
    if (c < 7) {  // stage next A chunk
      int k0 = (c + 1) * 32;
#pragma unroll
      for (int it = 0; it < 2; ++it) {
        int i = tid + it * 256;
        int row = i >> 3, part = i & 7;
        *(uint2*)&As[(c + 1) & 1][row * 36 + part * 4] =
            *(const uint2*)&A16[(size_t)(n0 + row) * 256 + k0 + part * 4];
      }
    }
    bf16x8 bc[2][2];
#pragma unroll
    for (int ks = 0; ks < 2; ++ks)
#pragma unroll
      for (int ct = 0; ct < 2; ++ct) bc[ks][ct] = bn[ks][ct];
    if (c < 7) {
      int k0 = (c + 1) * 32;
#pragma unroll
      for (int ks = 0; ks < 2; ++ks)
#pragma unroll
        for (int ct = 0; ct < 2; ++ct)
          bn[ks][ct] = *(const bf16x8*)&W16[
              (size_t)(w * 64 + ct * 32 + m31) * 256 + k0 + ks * 16 + half * 8];
    }
    const ushort* ab = As[c & 1];
#pragma unroll
    for (int ks = 0; ks < 2; ++ks) {
      bf16x8 af[2];
#pragma unroll
      for (int rt = 0; rt < 2; ++rt) {
        union { bf16x8 v; uint2 u[2]; } t;
        const ushort* p = &ab[(rt * 32 + m31) * 36 + ks * 16 + half * 8];
        t.u[0] = *(const uint2*)p;
        t.u[1] = *(const uint2*)(p + 4);
        af[rt] = t.v;
      }
#pragma unroll
      for (int rt = 0; rt < 2; ++rt)
#pragma unroll
        for (int ct = 0; ct < 2; ++ct)
          acc[rt][ct] = __builtin_amdgcn_mfma_f32_32x32x16_bf16(
              af[rt], bc[ks][ct], acc[rt][ct], 0, 0, 0);
    }
  }
  // epilogue
#pragma unroll
  for (int ct = 0; ct < 2; ++ct) {
    int col = w * 64 + ct * 32 + m31;
    float bv = bias[col];
#pragma unroll
    for (int rt = 0; rt < 2; ++rt) {
#pragma unroll
      for (int reg = 0; reg < 16; ++reg) {
        int row = n0 + rt * 32 + (reg & 3) + 8 * (reg >> 2) + 4 * half;
        float v = acc[rt][ct][reg] + bv;
        if (ACT == 1) v = mishf_(v);
        if (RESID) v += resid[(size_t)row * 256 + col];
        if (OUTF32) outf[(size_t)row * 256 + col] = v;
        if (OUTB16) outb[(size_t)row * 256 + col] = f2bf_(v);
      }
    }
  }
}

// ---------------------------------------------------------------------------
// Conv1dGLU bf16 MFMA implicit GEMM. K = 5 taps x 256 cin. Block = 128 rows
// x 256 out-cols (128 a-ch + paired 128 g-ch); waves 0,1 = a-cols, 2,3 =
// g-cols; wave = 128 rows (R=4) x 64 cols (C=2). A: LDS rows n0-2..n0+129
// per cin-chunk (dbuf); B: global from WtT (k-contiguous), one-tap-ahead
// prefetch. Epilogue: g-waves write sigmoid(g) bf16 to LDS; a-waves do
// out = resid_f32 + (a+ba)*sig, write fp32+bf16 (+ mask-zeroing).
// ---------------------------------------------------------------------------
template <int DO_MASK>
__global__ __launch_bounds__(256, 1) void conv_mfma_kernel(
    const ushort* __restrict__ H16, const float* __restrict__ Hf,
    const ushort* __restrict__ WtT, const float* __restrict__ cb,
    const float* __restrict__ fmask, float* __restrict__ outf,
    ushort* __restrict__ outb) {
  __shared__ ushort As[2][132 * 36];
  __shared__ ushort Sg[128 * 132];
  int tid = threadIdx.x;
  int w = tid >> 6, lane = tid & 63;
  int m31 = lane & 31, half = lane >> 5;
  int cg = blockIdx.x;             // 0..1: 128-channel group
  int n0 = blockIdx.y * 128;
  int tbase = n0 & 1023;
  int isG = w >> 1, wc = w & 1;
  int colbase = (isG ? 256 : 0) + cg * 128 + wc * 64;  // + ct*32 + m31

  floatx16 acc[4][2];
#pragma unroll
  for (int a = 0; a < 4; ++a)
#pragma unroll
    for (int b = 0; b < 2; ++b)
#pragma unroll
      for (int i = 0; i < 16; ++i) acc[a][b][i] = 0.f;

  // stage A chunk 0 (rows n0-2 .. n0+129, zero-padded at batch edges)
  for (int i = tid; i < 1056; i += 256) {
    int row = i >> 3, part = i & 7;
    int t = tbase + row - 2;
    uint2 v = make_uint2(0u, 0u);
    if ((unsigned)t < 1024u)
      v = *(const uint2*)&H16[(size_t)(n0 + row - 2) * 256 + part * 4];
    *(uint2*)&As[0][row * 36 + part * 4] = v;
  }
  // prefetch B (chunk 0, tap 0)
  bf16x8 bn[2][2];
#pragma unroll
  for (int ks = 0; ks < 2; ++ks)
#pragma unroll
    for (int ct = 0; ct < 2; ++ct)
      bn[ks][ct] = *(const bf16x8*)&WtT[(size_t)(colbase + ct * 32 + m31) * 1280 +
                                        ks * 16 + half * 8];

  for (int c = 0; c < 8; ++c) {
    __syncthreads();
    if (c < 7) {
      int k0 = (c + 1) * 32;
      for (int i = tid; i < 1056; i += 256) {
        int row = i >> 3, part = i & 7;
        int t = tbase + row - 2;
        uint2 v = make_uint2(0u, 0u);
        if ((unsigned)t < 1024u)
          v = *(const uint2*)&H16[(size_t)(n0 + row - 2) * 256 + k0 + part * 4];
        *(uint2*)&As[(c + 1) & 1][row * 36 + part * 4] = v;
      }
    }
    const ushort* ab = As[c & 1];
#pragma unroll
    for (int tap = 0; tap < 5; ++tap) {
      bf16x8 bc[2][2];
#pragma unroll
      for (int ks = 0; ks < 2; ++ks)
#pragma unroll
        for (int ct = 0; ct < 2; ++ct) bc[ks][ct] = bn[ks][ct];
      // prefetch next (tap+1) or (chunk+1, tap 0)
      int pc = c, pt = tap + 1;
      if (pt == 5) { pc = c + 1; pt = 0; }
      if (pc < 8) {
#pragma unroll
        for (int ks = 0; ks < 2; ++ks)
#pragma unroll
          for (int ct = 0; ct < 2; ++ct)
            bn[ks][ct] = *(const bf16x8*)&WtT[
                (size_t)(colbase + ct * 32 + m31) * 1280 + pt * 256 + pc * 32 +
                ks * 16 + half * 8];
      }
#pragma unroll
      for (int ks = 0; ks < 2; ++ks) {
        bf16x8 af[4];
#pragma unroll
        for (int rt = 0; rt < 4; ++rt) {
          union { bf16x8 v; uint2 u[2]; } t;
          const ushort* p = &ab[(rt * 32 + m31 + tap) * 36 + ks * 16 + half * 8];
          t.u[0] = *(const uint2*)p;
          t.u[1] = *(const uint2*)(p + 4);
          af[rt] = t.v;
        }
#pragma unroll
        for (int rt = 0; rt < 4; ++rt)
#pragma unroll
          for (int ct = 0; ct < 2; ++ct)
            acc[rt][ct] = __builtin_amdgcn_mfma_f32_32x32x16_bf16(
                af[rt], bc[ks][ct], acc[rt][ct], 0, 0, 0);
      }
    }
  }
  // ---- GLU epilogue ----
  if (isG) {
#pragma unroll
    for (int ct = 0; ct < 2; ++ct) {
      int c128 = wc * 64 + ct * 32 + m31;
      float bg = cb[256 + cg * 128 + c128];
#pragma unroll
      for (int rt = 0; rt < 4; ++rt)
#pragma unroll
        for (int reg = 0; reg < 16; ++reg) {
          int brow = rt * 32 + (reg & 3) + 8 * (reg >> 2) + 4 * half;
          Sg[brow * 132 + c128] = f2bf_(sigmoidf_(acc[rt][ct][reg] + bg));
        }
    }
  }
  __syncthreads();
  if (!isG) {
#pragma unroll
    for (int ct = 0; ct < 2; ++ct) {
      int c128 = wc * 64 + ct * 32 + m31;
      int gcol = cg * 128 + c128;
      float ba = cb[gcol];
#pragma unroll
      for (int rt = 0; rt < 4; ++rt)
#pragma unroll
        for (int reg = 0; reg < 16; ++reg) {
          int brow = rt * 32 + (reg & 3) + 8 * (reg >> 2) + 4 * half;
          int grow = n0 + brow;
          float sig = bf2f_(Sg[brow * 132 + c128]);
          float v = Hf[(size_t)grow * 256 + gcol] +
                    (acc[rt][ct][reg] + ba) * sig;
          if (DO_MASK) {
            if (fmask[grow] != 0.f) v = 0.f;
          }
          outf[(size_t)grow * 256 + gcol] = v;
          outb[(size_t)grow * 256 + gcol] = f2bf_(v);
        }
    }
  }
}

// ---------------------------------------------------------------------------
// bf16 MFMA flash attention (16x16x32 shapes), bf16 out for the out-proj.
// ---------------------------------------------------------------------------
__global__ __launch_bounds__(256) void attn_mfma_kernel(
    const ushort* __restrict__ Q, const ushort* __restrict__ K,
    const ushort* __restrict__ V, const float* __restrict__ fmask,
    ushort* __restrict__ O) {
  __shared__ ushort Kt[32][136];
  __shared__ ushort Vf[4096];
  __shared__ ushort Pw[4][16][40];
  __shared__ float kmask[32];
  int tid = threadIdx.x;
  int w = tid >> 6, lane = tid & 63;
  int quad = lane >> 4, l16 = lane & 15;
  int b = blockIdx.y >> 1, h = blockIdx.y & 1;
  int qw0 = blockIdx.x * 64 + w * 16;
  size_t rowQ = (size_t)(b * 1024 + qw0 + l16) * 256 + h * 128;
  bf16x8 qf[4];
#pragma unroll
  for (int c = 0; c < 4; ++c)
    qf[c] = *(const bf16x8*)&Q[rowQ + c * 32 + quad * 8];
  floatx4 oacc[8];
#pragma unroll
  for (int n = 0; n < 8; ++n) oacc[n] = (floatx4){0.f, 0.f, 0.f, 0.f};
  float mi[4] = {-1e30f, -1e30f, -1e30f, -1e30f};
  float li[4] = {0.f, 0.f, 0.f, 0.f};
  size_t kvbase = (size_t)(b * 1024) * 256 + h * 128;
  for (int kt0 = 0; kt0 < 1024; kt0 += 32) {
    __syncthreads();
#pragma unroll
    for (int r = 0; r < 2; ++r) {
      int cid = tid + r * 256;
      int row = cid >> 4, off8 = (cid & 15) * 8;
      *(uint4*)&Kt[row][off8] =
          *(const uint4*)&K[kvbase + (size_t)(kt0 + row) * 256 + off8];
      uint4 vv = *(const uint4*)&V[kvbase + (size_t)(kt0 + row) * 256 + off8];
      const ushort* pv = (const ushort*)&vv;
      int qp = row >> 3, j = row & 7;
#pragma unroll
      for (int i = 0; i < 8; ++i) {
        int dv = off8 + i;
        Vf[(((dv >> 4) * 4 + qp) * 16 + (dv & 15)) * 8 + j] = pv[i];
      }
    }
    if (tid < 32) kmask[tid] = fmask[b * 1024 + kt0 + tid];
    __syncthreads();
    floatx4 sa0 = {0.f, 0.f, 0.f, 0.f}, sa1 = {0.f, 0.f, 0.f, 0.f};
#pragma unroll
    for (int c = 0; c < 4; ++c) {
      bf16x8 k0f = *(const bf16x8*)&Kt[l16][c * 32 + quad * 8];
      bf16x8 k1f = *(const bf16x8*)&Kt[16 + l16][c * 32 + quad * 8];
      sa0 = __builtin_amdgcn_mfma_f32_16x16x32_bf16(qf[c], k0f, sa0, 0, 0, 0);
      sa1 = __builtin_amdgcn_mfma_f32_16x16x32_bf16(qf[c], k1f, sa1, 0, 0, 0);
    }
    float km0 = kmask[l16], km1 = kmask[16 + l16];
    float alpha[4];
#pragma unroll
    for (int r = 0; r < 4; ++r) {
      float s0 = (km0 != 0.f) ? -1e30f : sa0[r] * 0.0625f;
      float s1 = (km1 != 0.f) ? -1e30f : sa1[r] * 0.0625f;
      float mt = fmaxf(s0, s1);
      mt = fmaxf(mt, __shfl_xor(mt, 1));
      mt = fmaxf(mt, __shfl_xor(mt, 2));
      mt = fmaxf(mt, __shfl_xor(mt, 4));
      mt = fmaxf(mt, __shfl_xor(mt, 8));
      float mnew = fmaxf(mi[r], mt);
      alpha[r] = __expf(mi[r] - mnew);
      bool dead = (mnew <= -1e29f);
      float p0 = dead ? 0.f : __expf(s0 - mnew);
      float p1 = dead ? 0.f : __expf(s1 - mnew);
      float rs = p0 + p1;
      rs += __shfl_xor(rs, 1);
      rs += __shfl_xor(rs, 2);
      rs += __shfl_xor(rs, 4);
      rs += __shfl_xor(rs, 8);
      li[r] = li[r] * alpha[r] + rs;
      mi[r] = mnew;
      Pw[w][quad * 4 + r][l16] = f2bf_(p0);
      Pw[w][quad * 4 + r][16 + l16] = f2bf_(p1);
    }
    __syncthreads();
    bf16x8 pf = *(const bf16x8*)&Pw[w][l16][quad * 8];
#pragma unroll
    for (int n = 0; n < 8; ++n) {
      floatx4 o = oacc[n];
      o[0] *= alpha[0]; o[1] *= alpha[1]; o[2] *= alpha[2]; o[3] *= alpha[3];
      bf16x8 vf = *(const bf16x8*)&Vf[((n * 4 + quad) * 16 + l16) * 8];
      oacc[n] = __builtin_amdgcn_mfma_f32_16x16x32_bf16(pf, vf, o, 0, 0, 0);
    }
  }
  float inv[4];
#pragma unroll
  for (int r = 0; r < 4; ++r) inv[r] = (li[r] > 0.f) ? 1.f / li[r] : 0.f;
#pragma unroll
  for (int n = 0; n < 8; ++n)
#pragma unroll
    for (int r = 0; r < 4; ++r)
      O[kvbase + (size_t)(qw0 + quad * 4 + r) * 256 + n * 16 + l16] =
          f2bf_(oacc[n][r] * inv[r]);
}

// ---------------------------------------------------------------------------
// Pooling + final projection (pool-then-project).
// ---------------------------------------------------------------------------
__global__ __launch_bounds__(256) void pool_prep_kernel(
    const float* __restrict__ fmask, float* __restrict__ pooled,
    float* __restrict__ lenb) {
  int b = blockIdx.x, tid = threadIdx.x;
  pooled[b * 256 + tid] = 0.f;
  float c = 0.f;
  for (int i = 0; i < 4; ++i)
    c += (fmask[b * 1024 + i * 256 + tid] == 0.f) ? 1.f : 0.f;
  __shared__ float red[256];
  red[tid] = c;
  __syncthreads();
  for (int s = 128; s > 0; s >>= 1) {
    if (tid < s) red[tid] += red[tid + s];
    __syncthreads();
  }
  if (tid == 0) lenb[b] = red[0];
}

__global__ __launch_bounds__(256) void pool_kernel(
    const float* __restrict__ h5, const float* __restrict__ fmask,
    float* __restrict__ pooled) {
  int ch = blockIdx.x, b = blockIdx.y, d = threadIdx.x;
  float s = 0.f;
  for (int i = 0; i < 32; ++i) {
    int t = ch * 32 + i;
    if (fmask[b * 1024 + t] == 0.f)
      s += h5[((size_t)b * 1024 + t) * 256 + d];
  }
  atomicAdd(&pooled[b * 256 + d], s);
}

__global__ __launch_bounds__(256) void final_kernel(
    const float* __restrict__ pooled, const float* __restrict__ lenb,
    const float* __restrict__ Wf, const float* __restrict__ bf,
    float* __restrict__ out) {
  int b = blockIdx.x, j = threadIdx.x;
  __shared__ __align__(16) float p[256];
  p[j] = pooled[b * 256 + j];
  __syncthreads();
  const float* w = Wf + (size_t)j * 256;
  float s = 0.f;
  for (int d4 = 0; d4 < 64; ++d4) {
    float4 wv = ((const float4*)w)[d4];
    float4 pv = ((const float4*)p)[d4];
    s += wv.x * pv.x + wv.y * pv.y + wv.z * pv.z + wv.w * pv.w;
  }
  float len = lenb[b];
  float inv = (len > 0.f) ? 1.f / len : 0.f;
  out[b * 256 + j] = s * inv + bf[j];
}

// ---------------------------------------------------------------------------
extern "C" void kernel_launch(void* const* d_in, const int* in_sizes, int n_in,
                              void* d_out, int out_size, void* d_ws, size_t ws_size,
                              hipStream_t stream) {
  const float* x      = (const float*)d_in[0];
  const unsigned* msk = (const unsigned*)d_in[1];
  const float* W1 = (const float*)d_in[2];
  const float* b1 = (const float*)d_in[3];
  const float* W2 = (const float*)d_in[4];
  const float* b2 = (const float*)d_in[5];
  const float* cW1 = (const float*)d_in[6];
  const float* cb1 = (const float*)d_in[7];
  const float* cW2 = (const float*)d_in[8];
  const float* cb2 = (const float*)d_in[9];
  const float* Wq = (const float*)d_in[10];
  const float* bq = (const float*)d_in[11];
  const float* Wk = (const float*)d_in[12];
  const float* bk = (const float*)d_in[13];
  const float* Wv = (const float*)d_in[14];
  const float* bv = (const float*)d_in[15];
  const float* Wo = (const float*)d_in[16];
  const float* bo = (const float*)d_in[17];
  const float* Wf = (const float*)d_in[18];
  const float* bf = (const float*)d_in[19];
  float* out = (float*)d_out;

  // workspace layout: fp32 region first, then bf16 region (~71 MB total)
  float* ws = (float*)d_ws;
  size_t ND = (size_t)N_ * D_;  // 4194304
  float* F0     = ws;                    // fp32 residual stream (ping)
  float* F1     = F0 + ND;               // fp32 residual stream (pong)
  float* fmask  = F1 + ND;               // [16384]
  float* pooled = fmask + N_;            // [4096]
  float* lenb   = pooled + B_ * D_;      // [16]
  ushort* G0 = (ushort*)(lenb + 16);     // bf16 activation buffers
  ushort* G1 = G0 + ND;
  ushort* G2 = G1 + ND;
  ushort* G3 = G2 + ND;
  ushort* w1_16 = G3 + ND;               // 6 x 65536 bf16 weights
  ushort* w2_16 = w1_16 + 65536;
  ushort* wq_16 = w2_16 + 65536;
  ushort* wk_16 = wq_16 + 65536;
  ushort* wv_16 = wk_16 + 65536;
  ushort* wo_16 = wv_16 + 65536;
  ushort* WtT1  = wo_16 + 65536;         // [512*1280] bf16 conv weights
  ushort* WtT2  = WtT1 + 512 * 1280;

  dim3 blk(256);
  // prep
  mask_prep_kernel<<<dim3(64), blk, 0, stream>>>(msk, fmask);
  cast_f2b_kernel<<<dim3(4096), blk, 0, stream>>>(x, G0, (int)(ND / 4));
  cast_f2b_kernel<<<dim3(64), blk, 0, stream>>>(W1, w1_16, 16384);
  cast_f2b_kernel<<<dim3(64), blk, 0, stream>>>(W2, w2_16, 16384);
  cast_f2b_kernel<<<dim3(64), blk, 0, stream>>>(Wq, wq_16, 16384);
  cast_f2b_kernel<<<dim3(64), blk, 0, stream>>>(Wk, wk_16, 16384);
  cast_f2b_kernel<<<dim3(64), blk, 0, stream>>>(Wv, wv_16, 16384);
  cast_f2b_kernel<<<dim3(64), blk, 0, stream>>>(Wo, wo_16, 16384);
  conv_w_prep_kernel<<<dim3(2560), blk, 0, stream>>>(cW1, WtT1);
  conv_w_prep_kernel<<<dim3(2560), blk, 0, stream>>>(cW2, WtT2);
  // spectral MLP: h1 = mish(x@W1^T+b1) [bf16]; h2 = mish(h1@W2^T+b2) [bf16+f32]
  gemm_mfma_kernel<1, 0, 0, 1><<<dim3(256), blk, 0, stream>>>(
      G0, w1_16, b1, nullptr, nullptr, G1);
  gemm_mfma_kernel<1, 0, 1, 1><<<dim3(256), blk, 0, stream>>>(
      G1, w2_16, b2, nullptr, F0, G0);
  // conv GLU x2 (second fuses mask-zeroing)
  conv_mfma_kernel<0><<<dim3(2, 128), blk, 0, stream>>>(
      G0, F0, WtT1, cb1, fmask, F1, G1);
  conv_mfma_kernel<1><<<dim3(2, 128), blk, 0, stream>>>(
      G1, F1, WtT2, cb2, fmask, F0, G0);
  // attention: QKV bf16, flash MFMA, bf16 out
  gemm_mfma_kernel<0, 0, 0, 1><<<dim3(256), blk, 0, stream>>>(
      G0, wq_16, bq, nullptr, nullptr, G1);
  gemm_mfma_kernel<0, 0, 0, 1><<<dim3(256), blk, 0, stream>>>(
      G0, wk_16, bk, nullptr, nullptr, G2);
  gemm_mfma_kernel<0, 0, 0, 1><<<dim3(256), blk, 0, stream>>>(
      G0, wv_16, bv, nullptr, nullptr, G3);
  attn_mfma_kernel<<<dim3(16, 32), blk, 0, stream>>>(G1, G2, G3, fmask, G0);
  // out-proj + residual -> h5 fp32
  gemm_mfma_kernel<0, 1, 1, 0><<<dim3(256), blk, 0, stream>>>(
      G0, wo_16, bo, F0, F1, nullptr);
  // pool-then-project final layer
  pool_prep_kernel<<<dim3(16), blk, 0, stream>>>(fmask, pooled, lenb);
  pool_kernel<<<dim3(32, 16), blk, 0, stream>>>(F1, fmask, pooled);
  final_kernel<<<dim3(16), blk, 0, stream>>>(pooled, lenb, Wf, bf, out);
}

// Round 4
// 462.011 us; speedup vs baseline: 2.9440x; 1.0878x over previous
//
#include <hip/hip_runtime.h>
#include <hip/hip_bf16.h>
#include <math.h>

// ============================================================================
// StylePredictor. Round 4: LDS-free flash attention (S^T/O^T orientation,
// xor-32 P exchange, mask as rank-1 MFMA bias column, V pre-transposed).
// Conv + dense GEMMs unchanged from round 3 (bf16 MFMA 32x32x16).
// ============================================================================

#define DEV __device__ __forceinline__

static constexpr int B_ = 16, T_ = 1024, D_ = 256;
static constexpr int N_ = B_ * T_;

typedef __attribute__((ext_vector_type(8))) short bf16x8;
typedef __attribute__((ext_vector_type(16))) float floatx16;

DEV float sigmoidf_(float x) { return 1.f / (1.f + __expf(-x)); }
DEV float mishf_(float x) {
  float sp = (x > 20.f) ? x : log1pf(expf(x));
  return x * tanhf(sp);
}
DEV ushort f2bf_(float x) {
  __hip_bfloat16 h = __float2bfloat16(x);
  return *(ushort*)&h;
}
DEV float bf2f_(ushort u) {
  unsigned v = ((unsigned)u) << 16;
  return *(float*)&v;
}

// ---------------------------------------------------------------------------
// Mask prep: detect bool storage (int32 / int8 / fp32), emit fp32 fmask
// (1.0 = masked -> zero the frame).
// ---------------------------------------------------------------------------
__global__ __launch_bounds__(256) void mask_prep_kernel(
    const unsigned* __restrict__ mraw, float* __restrict__ fmask) {
  int tid = threadIdx.x;
  int isByte = 0, isFloat = 0;
  for (int i = 0; i < 16; ++i) {
    unsigned v = mraw[tid * 16 + i];
    if (v == 0x3F800000u) isFloat = 1;
    else if (v > 1u) isByte = 1;
  }
  __shared__ int sByte, sFloat;
  if (tid == 0) { sByte = 0; sFloat = 0; }
  __syncthreads();
  if (isByte) atomicOr(&sByte, 1);
  if (isFloat) atomicOr(&sFloat, 1);
  __syncthreads();
  int mode = sFloat ? 2 : (sByte ? 1 : 0);
  int idx = blockIdx.x * 256 + tid;
  unsigned mv;
  if (mode == 1) mv = ((const unsigned char*)mraw)[idx];
  else           mv = mraw[idx];
  fmask[idx] = (mv != 0u) ? 1.f : 0.f;
}

// ---------------------------------------------------------------------------
// fp32 -> bf16 bulk cast.
// ---------------------------------------------------------------------------
__global__ __launch_bounds__(256) void cast_f2b_kernel(
    const float* __restrict__ src, ushort* __restrict__ dst, int n4) {
  int i = blockIdx.x * 256 + threadIdx.x;
  if (i >= n4) return;
  float4 v = ((const float4*)src)[i];
  ushort4 u;
  u.x = f2bf_(v.x); u.y = f2bf_(v.y); u.z = f2bf_(v.z); u.w = f2bf_(v.w);
  ((ushort4*)dst)[i] = u;
}

// ---------------------------------------------------------------------------
// Conv weight prep: wtT[co*1280 + k*256 + cin] = bf16(cw[(co*256+cin)*5 + k])
// ---------------------------------------------------------------------------
__global__ __launch_bounds__(256) void conv_w_prep_kernel(
    const float* __restrict__ cw, ushort* __restrict__ wtT) {
  int i = blockIdx.x * 256 + threadIdx.x;
  if (i >= 512 * 1280) return;
  int co = i / 1280;
  int r = i - co * 1280;
  int k = r >> 8;
  int cin = r & 255;
  wtT[i] = f2bf_(cw[(size_t)(co * 256 + cin) * 5 + k]);
}

// ---------------------------------------------------------------------------
// Fill the bias chunk (cols 128..143) of QE/KE rows:
//   QE: {1, 0 x15}    KE: {mask? -60000 : 0, 0 x15}
// ---------------------------------------------------------------------------
__global__ __launch_bounds__(256) void qk_ext_fill_kernel(
    const float* __restrict__ fmask, ushort* __restrict__ QE,
    ushort* __restrict__ KE) {
  int i = blockIdx.x * 256 + threadIdx.x;   // bh*1024 + t, 32768 total
  int bh = i >> 10, t = i & 1023, b = bh >> 2 * 0 + (bh >> 1);  // b = bh>>1
  b = bh >> 1;
  size_t base = (size_t)i * 144 + 128;
  ushort mb = f2bf_((fmask[b * 1024 + t] != 0.f) ? -60000.f : 0.f);
  QE[base] = f2bf_(1.f);
  KE[base] = mb;
#pragma unroll
  for (int j = 1; j < 16; ++j) { QE[base + j] = 0; KE[base + j] = 0; }
}

// ---------------------------------------------------------------------------
// bf16 MFMA GEMM: C = act(A @ W^T + bias) [+resid].
// Block = 64 rows x 256 cols, 4 waves; wave = 64x64, 2x2 tiles of 32x32.
// OMODE: 0 = f32 [N,256]; 1 = bf16 [N,256]; 2 = both;
//        3 = QE layout (x1/16, stride 144, [bh][t][dk]);
//        4 = KE layout (stride 144);
//        5 = VT layout ([bh][dv][t] transposed).
// 32x32x16 layouts: A/B [m|n=lane&31][k=(lane>>5)*8+j];
// C/D col=lane&31, row=(reg&3)+8*(reg>>2)+4*(lane>>5).
// ---------------------------------------------------------------------------
template <int ACT, int RESID, int OMODE>
__global__ __launch_bounds__(256, 2) void gemm_mfma_kernel(
    const ushort* __restrict__ A16, const ushort* __restrict__ W16,
    const float* __restrict__ bias, const float* __restrict__ resid,
    float* __restrict__ outf, ushort* __restrict__ outb) {
  __shared__ ushort As[2][64 * 36];
  int tid = threadIdx.x;
  int w = tid >> 6, lane = tid & 63;
  int m31 = lane & 31, half = lane >> 5;
  int n0 = blockIdx.x * 64;

  floatx16 acc[2][2];
#pragma unroll
  for (int a = 0; a < 2; ++a)
#pragma unroll
    for (int b = 0; b < 2; ++b)
#pragma unroll
      for (int i = 0; i < 16; ++i) acc[a][b][i] = 0.f;

#pragma unroll
  for (int it = 0; it < 2; ++it) {
    int i = tid + it * 256;
    int row = i >> 3, part = i & 7;
    *(uint2*)&As[0][row * 36 + part * 4] =
        *(const uint2*)&A16[(size_t)(n0 + row) * 256 + part * 4];
  }
  bf16x8 bn[2][2];
#pragma unroll
  for (int ks = 0; ks < 2; ++ks)
#pragma unroll
    for (int ct = 0; ct < 2; ++ct)
      bn[ks][ct] = *(const bf16x8*)&W16[(size_t)(w * 64 + ct * 32 + m31) * 256 +
                                        ks * 16 + half * 8];

  for (int c = 0; c < 8; ++c) {
    __syncthreads();
    if (c < 7) {
      int k0 = (c + 1) * 32;
#pragma unroll
      for (int it = 0; it < 2; ++it) {
        int i = tid + it * 256;
        int row = i >> 3, part = i & 7;
        *(uint2*)&As[(c + 1) & 1][row * 36 + part * 4] =
            *(const uint2*)&A16[(size_t)(n0 + row) * 256 + k0 + part * 4];
      }
    }
    bf16x8 bc[2][2];
#pragma unroll
    for (int ks = 0; ks < 2; ++ks)
#pragma unroll
      for (int ct = 0; ct < 2; ++ct) bc[ks][ct] = bn[ks][ct];
    if (c < 7) {
      int k0 = (c + 1) * 32;
#pragma unroll
      for (int ks = 0; ks < 2; ++ks)
#pragma unroll
        for (int ct = 0; ct < 2; ++ct)
          bn[ks][ct] = *(const bf16x8*)&W16[
              (size_t)(w * 64 + ct * 32 + m31) * 256 + k0 + ks * 16 + half * 8];
    }
    const ushort* ab = As[c & 1];
#pragma unroll
    for (int ks = 0; ks < 2; ++ks) {
      bf16x8 af[2];
#pragma unroll
      for (int rt = 0; rt < 2; ++rt) {
        union { bf16x8 v; uint2 u[2]; } t;
        const ushort* p = &ab[(rt * 32 + m31) * 36 + ks * 16 + half * 8];
        t.u[0] = *(const uint2*)p;
        t.u[1] = *(const uint2*)(p + 4);
        af[rt] = t.v;
      }
#pragma unroll
      for (int rt = 0; rt < 2; ++rt)
#pragma unroll
        for (int ct = 0; ct < 2; ++ct)
          acc[rt][ct] = __builtin_amdgcn_mfma_f32_32x32x16_bf16(
              af[rt], bc[ks][ct], acc[rt][ct], 0, 0, 0);
    }
  }
  // epilogue
#pragma unroll
  for (int ct = 0; ct < 2; ++ct) {
    int col = w * 64 + ct * 32 + m31;
    float bv = bias[col];
    if (OMODE == 5) {
      int h = col >> 7, dk = col & 127;
      int b = n0 >> 10;
      size_t vbase = ((size_t)((b * 2 + h) * 128 + dk)) * 1024;
#pragma unroll
      for (int rt = 0; rt < 2; ++rt)
#pragma unroll
        for (int rg = 0; rg < 4; ++rg) {
          ushort4 u;
          u.x = f2bf_(acc[rt][ct][rg * 4 + 0] + bv);
          u.y = f2bf_(acc[rt][ct][rg * 4 + 1] + bv);
          u.z = f2bf_(acc[rt][ct][rg * 4 + 2] + bv);
          u.w = f2bf_(acc[rt][ct][rg * 4 + 3] + bv);
          int t0 = (n0 & 1023) + rt * 32 + 8 * rg + 4 * half;
          *(ushort4*)&outb[vbase + t0] = u;
        }
    } else {
#pragma unroll
      for (int rt = 0; rt < 2; ++rt) {
#pragma unroll
        for (int reg = 0; reg < 16; ++reg) {
          int row = n0 + rt * 32 + (reg & 3) + 8 * (reg >> 2) + 4 * half;
          float v = acc[rt][ct][reg] + bv;
          if (ACT == 1) v = mishf_(v);
          if (RESID) v += resid[(size_t)row * 256 + col];
          if (OMODE == 0) {
            outf[(size_t)row * 256 + col] = v;
          } else if (OMODE == 1) {
            outb[(size_t)row * 256 + col] = f2bf_(v);
          } else if (OMODE == 2) {
            outf[(size_t)row * 256 + col] = v;
            outb[(size_t)row * 256 + col] = f2bf_(v);
          } else {  // 3 / 4
            int b = row >> 10, t = row & 1023, h = col >> 7, dk = col & 127;
            size_t addr = ((size_t)((b * 2 + h) * 1024 + t)) * 144 + dk;
            outb[addr] = f2bf_(OMODE == 3 ? v * 0.0625f : v);
          }
        }
      }
    }
  }
}

// ---------------------------------------------------------------------------
// Conv1dGLU bf16 MFMA implicit GEMM (unchanged from round 3).
// ---------------------------------------------------------------------------
template <int DO_MASK>
__global__ __launch_bounds__(256, 1) void conv_mfma_kernel(
    const ushort* __restrict__ H16, const float* __restrict__ Hf,
    const ushort* __restrict__ WtT, const float* __restrict__ cb,
    const float* __restrict__ fmask, float* __restrict__ outf,
    ushort* __restrict__ outb) {
  __shared__ ushort As[2][132 * 36];
  __shared__ ushort Sg[128 * 132];
  int tid = threadIdx.x;
  int w = tid >> 6, lane = tid & 63;
  int m31 = lane & 31, half = lane >> 5;
  int cg = blockIdx.x;
  int n0 = blockIdx.y * 128;
  int tbase = n0 & 1023;
  int isG = w >> 1, wc = w & 1;
  int colbase = (isG ? 256 : 0) + cg * 128 + wc * 64;

  floatx16 acc[4][2];
#pragma unroll
  for (int a = 0; a < 4; ++a)
#pragma unroll
    for (int b = 0; b < 2; ++b)
#pragma unroll
      for (int i = 0; i < 16; ++i) acc[a][b][i] = 0.f;

  for (int i = tid; i < 1056; i += 256) {
    int row = i >> 3, part = i & 7;
    int t = tbase + row - 2;
    uint2 v = make_uint2(0u, 0u);
    if ((unsigned)t < 1024u)
      v = *(const uint2*)&H16[(size_t)(n0 + row - 2) * 256 + part * 4];
    *(uint2*)&As[0][row * 36 + part * 4] = v;
  }
  bf16x8 bn[2][2];
#pragma unroll
  for (int ks = 0; ks < 2; ++ks)
#pragma unroll
    for (int ct = 0; ct < 2; ++ct)
      bn[ks][ct] = *(const bf16x8*)&WtT[(size_t)(colbase + ct * 32 + m31) * 1280 +
                                        ks * 16 + half * 8];

  for (int c = 0; c < 8; ++c) {
    __syncthreads();
    if (c < 7) {
      int k0 = (c + 1) * 32;
      for (int i = tid; i < 1056; i += 256) {
        int row = i >> 3, part = i & 7;
        int t = tbase + row - 2;
        uint2 v = make_uint2(0u, 0u);
        if ((unsigned)t < 1024u)
          v = *(const uint2*)&H16[(size_t)(n0 + row - 2) * 256 + k0 + part * 4];
        *(uint2*)&As[(c + 1) & 1][row * 36 + part * 4] = v;
      }
    }
    const ushort* ab = As[c & 1];
#pragma unroll
    for (int tap = 0; tap < 5; ++tap) {
      bf16x8 bc[2][2];
#pragma unroll
      for (int ks = 0; ks < 2; ++ks)
#pragma unroll
        for (int ct = 0; ct < 2; ++ct) bc[ks][ct] = bn[ks][ct];
      int pc = c, pt = tap + 1;
      if (pt == 5) { pc = c + 1; pt = 0; }
      if (pc < 8) {
#pragma unroll
        for (int ks = 0; ks < 2; ++ks)
#pragma unroll
          for (int ct = 0; ct < 2; ++ct)
            bn[ks][ct] = *(const bf16x8*)&WtT[
                (size_t)(colbase + ct * 32 + m31) * 1280 + pt * 256 + pc * 32 +
                ks * 16 + half * 8];
      }
#pragma unroll
      for (int ks = 0; ks < 2; ++ks) {
        bf16x8 af[4];
#pragma unroll
        for (int rt = 0; rt < 4; ++rt) {
          union { bf16x8 v; uint2 u[2]; } t;
          const ushort* p = &ab[(rt * 32 + m31 + tap) * 36 + ks * 16 + half * 8];
          t.u[0] = *(const uint2*)p;
          t.u[1] = *(const uint2*)(p + 4);
          af[rt] = t.v;
        }
#pragma unroll
        for (int rt = 0; rt < 4; ++rt)
#pragma unroll
          for (int ct = 0; ct < 2; ++ct)
            acc[rt][ct] = __builtin_amdgcn_mfma_f32_32x32x16_bf16(
                af[rt], bc[ks][ct], acc[rt][ct], 0, 0, 0);
      }
    }
  }
  if (isG) {
#pragma unroll
    for (int ct = 0; ct < 2; ++ct) {
      int c128 = wc * 64 + ct * 32 + m31;
      float bg = cb[256 + cg * 128 + c128];
#pragma unroll
      for (int rt = 0; rt < 4; ++rt)
#pragma unroll
        for (int reg = 0; reg < 16; ++reg) {
          int brow = rt * 32 + (reg & 3) + 8 * (reg >> 2) + 4 * half;
          Sg[brow * 132 + c128] = f2bf_(sigmoidf_(acc[rt][ct][reg] + bg));
        }
    }
  }
  __syncthreads();
  if (!isG) {
#pragma unroll
    for (int ct = 0; ct < 2; ++ct) {
      int c128 = wc * 64 + ct * 32 + m31;
      int gcol = cg * 128 + c128;
      float ba = cb[gcol];
#pragma unroll
      for (int rt = 0; rt < 4; ++rt)
#pragma unroll
        for (int reg = 0; reg < 16; ++reg) {
          int brow = rt * 32 + (reg & 3) + 8 * (reg >> 2) + 4 * half;
          int grow = n0 + brow;
          float sig = bf2f_(Sg[brow * 132 + c128]);
          float v = Hf[(size_t)grow * 256 + gcol] +
                    (acc[rt][ct][reg] + ba) * sig;
          if (DO_MASK) {
            if (fmask[grow] != 0.f) v = 0.f;
          }
          outf[(size_t)grow * 256 + gcol] = v;
          outb[(size_t)grow * 256 + gcol] = f2bf_(v);
        }
    }
  }
}

// ---------------------------------------------------------------------------
// LDS-free bf16 MFMA flash attention.
// QE [bh][t][144] = Q/16 with bias chunk {1,0..}; KE [bh][t][144] = K with
// bias chunk {mask?-6e4:0, 0..}; VT [bh][dv][t]. O bf16 [N,256].
// Block = (b,h) x 64 q; wave (qt=w&1, kh=w>>1) owns 32 q x 512 keys.
// Main loop (64 keys/iter): S^T = KE.QE^T (2x9 MFMA, mask+scale folded in);
// softmax lane-local (C col = q = lane&31, one xor-32 reduce); P^T B-frags
// via xor-32 exchange (no LDS); O^T += VT.P^T (16 MFMA, V-frags from global).
// Epilogue: kh=1 partials -> LDS, kh=0 merges (online-softmax combine).
// ---------------------------------------------------------------------------
__global__ __launch_bounds__(256, 2) void attn_mfma2_kernel(
    const ushort* __restrict__ QE, const ushort* __restrict__ KE,
    const ushort* __restrict__ VT, ushort* __restrict__ O) {
  __shared__ float Op[2][128][33];
  __shared__ float Ml[2][2][32];
  int tid = threadIdx.x;
  int w = tid >> 6, lane = tid & 63;
  int m31 = lane & 31, half = lane >> 5;
  int qt = w & 1, kh = w >> 1;
  int bh = blockIdx.y;
  int q0 = blockIdx.x * 64 + qt * 32;

  // Q fragments (B-operand), 9 chunks including bias chunk
  bf16x8 qe[9];
  {
    size_t qrow = ((size_t)(bh * 1024 + q0 + m31)) * 144;
#pragma unroll
    for (int c = 0; c < 9; ++c)
      qe[c] = *(const bf16x8*)&QE[qrow + c * 16 + half * 8];
  }
  floatx16 oacc[4];
#pragma unroll
  for (int ct = 0; ct < 4; ++ct)
#pragma unroll
    for (int i = 0; i < 16; ++i) oacc[ct][i] = 0.f;
  float mi = -1e30f, li = 0.f;
  size_t kebase = (size_t)bh * 1024 * 144;
  size_t vtbase = (size_t)bh * 128 * 1024;

  for (int it = 0; it < 8; ++it) {
    int ktb = kh * 512 + it * 64;
    // S^T: two 32-kt subtiles, 9 k-chunks each (chunk 8 = mask bias)
    floatx16 s0, s1;
#pragma unroll
    for (int i = 0; i < 16; ++i) { s0[i] = 0.f; s1[i] = 0.f; }
#pragma unroll
    for (int c = 0; c < 9; ++c) {
      bf16x8 kf0 = *(const bf16x8*)&KE[kebase +
          (size_t)(ktb + m31) * 144 + c * 16 + half * 8];
      bf16x8 kf1 = *(const bf16x8*)&KE[kebase +
          (size_t)(ktb + 32 + m31) * 144 + c * 16 + half * 8];
      s0 = __builtin_amdgcn_mfma_f32_32x32x16_bf16(kf0, qe[c], s0, 0, 0, 0);
      s1 = __builtin_amdgcn_mfma_f32_32x32x16_bf16(kf1, qe[c], s1, 0, 0, 0);
    }
    float p[2][16];
#pragma unroll
    for (int r = 0; r < 16; ++r) { p[0][r] = s0[r]; p[1][r] = s1[r]; }
    // softmax (lane-local q = m31; partner holds other 16 kt rows)
    float mloc = p[0][0];
#pragma unroll
    for (int r = 1; r < 16; ++r) mloc = fmaxf(mloc, p[0][r]);
#pragma unroll
    for (int r = 0; r < 16; ++r) mloc = fmaxf(mloc, p[1][r]);
    float mt = fmaxf(mloc, __shfl_xor(mloc, 32));
    float mnew = fmaxf(mi, mt);
    float alpha = __expf(mi - mnew);
    bool dead = (mnew <= -3.0e4f);
    float sum = 0.f;
#pragma unroll
    for (int sub = 0; sub < 2; ++sub)
#pragma unroll
      for (int r = 0; r < 16; ++r) {
        float v = dead ? 0.f : __expf(p[sub][r] - mnew);
        p[sub][r] = v;
        sum += v;
      }
    sum += __shfl_xor(sum, 32);
    li = li * alpha + sum;
    mi = mnew;
#pragma unroll
    for (int ct = 0; ct < 4; ++ct)
#pragma unroll
      for (int i = 0; i < 16; ++i) oacc[ct][i] *= alpha;
    // exchange p (xor-32) -> P^T B-frags [n=q][k=kt=half*8+j]
    bf16x8 pf[4];
#pragma unroll
    for (int sub = 0; sub < 2; ++sub) {
      float tx[16];
#pragma unroll
      for (int r = 0; r < 16; ++r) tx[r] = __shfl_xor(p[sub][r], 32);
#pragma unroll
      for (int s = 0; s < 2; ++s) {
        union { bf16x8 v; ushort u[8]; } pk;
#pragma unroll
        for (int j = 0; j < 8; ++j) {
          int base = s * 8;
          float lo = (j < 4) ? p[sub][base + j] : tx[base + j - 4];
          float hi = (j < 4) ? tx[base + 4 + j] : p[sub][base + j];
          pk.u[j] = f2bf_(half ? hi : lo);
        }
        pf[sub * 2 + s] = pk.v;
      }
    }
    // O^T += VT . P^T   (A = V^T rows dv, k = kt)
#pragma unroll
    for (int s2 = 0; s2 < 4; ++s2)
#pragma unroll
      for (int ct = 0; ct < 4; ++ct) {
        bf16x8 vf = *(const bf16x8*)&VT[vtbase +
            (size_t)(ct * 32 + m31) * 1024 + ktb + s2 * 16 + half * 8];
        oacc[ct] = __builtin_amdgcn_mfma_f32_32x32x16_bf16(
            vf, pf[s2], oacc[ct], 0, 0, 0);
      }
  }
  // merge the two key-halves
  if (kh == 1) {
#pragma unroll
    for (int ct = 0; ct < 4; ++ct)
#pragma unroll
      for (int r = 0; r < 16; ++r) {
        int dv = ct * 32 + (r & 3) + 8 * (r >> 2) + 4 * half;
        Op[qt][dv][m31] = oacc[ct][r];
      }
    if (half == 0) { Ml[qt][0][m31] = mi; Ml[qt][1][m31] = li; }
  }
  __syncthreads();
  if (kh == 0) {
    float mB = Ml[qt][0][m31], lB = Ml[qt][1][m31];
    float m = fmaxf(mi, mB);
    float aA = __expf(mi - m), aB = __expf(mB - m);
    float l = li * aA + lB * aB;
    float inv = (l > 0.f) ? 1.f / l : 0.f;
    int b = bh >> 1, h = bh & 1;
    size_t rowbase = (size_t)(b * 1024 + q0 + m31) * 256 + h * 128;
#pragma unroll
    for (int ct = 0; ct < 4; ++ct)
#pragma unroll
      for (int rg = 0; rg < 4; ++rg) {
        int dv0 = ct * 32 + 8 * rg + 4 * half;
        ushort4 u;
        u.x = f2bf_((oacc[ct][rg * 4 + 0] * aA + Op[qt][dv0 + 0][m31] * aB) * inv);
        u.y = f2bf_((oacc[ct][rg * 4 + 1] * aA + Op[qt][dv0 + 1][m31] * aB) * inv);
        u.z = f2bf_((oacc[ct][rg * 4 + 2] * aA + Op[qt][dv0 + 2][m31] * aB) * inv);
        u.w = f2bf_((oacc[ct][rg * 4 + 3] * aA + Op[qt][dv0 + 3][m31] * aB) * inv);
        *(ushort4*)&O[rowbase + dv0] = u;
      }
  }
}

// ---------------------------------------------------------------------------
// Pooling + final projection.
// ---------------------------------------------------------------------------
__global__ __launch_bounds__(256) void pool_prep_kernel(
    const float* __restrict__ fmask, float* __restrict__ pooled,
    float* __restrict__ lenb) {
  int b = blockIdx.x, tid = threadIdx.x;
  pooled[b * 256 + tid] = 0.f;
  float c = 0.f;
  for (int i = 0; i < 4; ++i)
    c += (fmask[b * 1024 + i * 256 + tid] == 0.f) ? 1.f : 0.f;
  __shared__ float red[256];
  red[tid] = c;
  __syncthreads();
  for (int s = 128; s > 0; s >>= 1) {
    if (tid < s) red[tid] += red[tid + s];
    __syncthreads();
  }
  if (tid == 0) lenb[b] = red[0];
}

__global__ __launch_bounds__(256) void pool_kernel(
    const float* __restrict__ h5, const float* __restrict__ fmask,
    float* __restrict__ pooled) {
  int ch = blockIdx.x, b = blockIdx.y, d = threadIdx.x;
  float s = 0.f;
  for (int i = 0; i < 32; ++i) {
    int t = ch * 32 + i;
    if (fmask[b * 1024 + t] == 0.f)
      s += h5[((size_t)b * 1024 + t) * 256 + d];
  }
  atomicAdd(&pooled[b * 256 + d], s);
}

__global__ __launch_bounds__(256) void final_kernel(
    const float* __restrict__ pooled, const float* __restrict__ lenb,
    const float* __restrict__ Wf, const float* __restrict__ bf,
    float* __restrict__ out) {
  int b = blockIdx.x, j = threadIdx.x;
  __shared__ __align__(16) float p[256];
  p[j] = pooled[b * 256 + j];
  __syncthreads();
  const float* w = Wf + (size_t)j * 256;
  float s = 0.f;
  for (int d4 = 0; d4 < 64; ++d4) {
    float4 wv = ((const float4*)w)[d4];
    float4 pv = ((const float4*)p)[d4];
    s += wv.x * pv.x + wv.y * pv.y + wv.z * pv.z + wv.w * pv.w;
  }
  float len = lenb[b];
  float inv = (len > 0.f) ? 1.f / len : 0.f;
  out[b * 256 + j] = s * inv + bf[j];
}

// ---------------------------------------------------------------------------
extern "C" void kernel_launch(void* const* d_in, const int* in_sizes, int n_in,
                              void* d_out, int out_size, void* d_ws, size_t ws_size,
                              hipStream_t stream) {
  const float* x      = (const float*)d_in[0];
  const unsigned* msk = (const unsigned*)d_in[1];
  const float* W1 = (const float*)d_in[2];
  const float* b1 = (const float*)d_in[3];
  const float* W2 = (const float*)d_in[4];
  const float* b2 = (const float*)d_in[5];
  const float* cW1 = (const float*)d_in[6];
  const float* cb1 = (const float*)d_in[7];
  const float* cW2 = (const float*)d_in[8];
  const float* cb2 = (const float*)d_in[9];
  const float* Wq = (const float*)d_in[10];
  const float* bq = (const float*)d_in[11];
  const float* Wk = (const float*)d_in[12];
  const float* bk = (const float*)d_in[13];
  const float* Wv = (const float*)d_in[14];
  const float* bv = (const float*)d_in[15];
  const float* Wo = (const float*)d_in[16];
  const float* bo = (const float*)d_in[17];
  const float* Wf = (const float*)d_in[18];
  const float* bf = (const float*)d_in[19];
  float* out = (float*)d_out;

  float* ws = (float*)d_ws;
  size_t ND = (size_t)N_ * D_;  // 4194304
  float* F0     = ws;
  float* F1     = F0 + ND;
  float* fmask  = F1 + ND;
  float* pooled = fmask + N_;
  float* lenb   = pooled + B_ * D_;
  ushort* G0 = (ushort*)(lenb + 16);
  ushort* G1 = G0 + ND;
  ushort* QE = G1 + ND;                  // [32][1024][144]
  ushort* KE = QE + (size_t)32 * 1024 * 144;
  ushort* VT = KE + (size_t)32 * 1024 * 144;   // [32][128][1024]
  ushort* w1_16 = VT + (size_t)32 * 128 * 1024;
  ushort* w2_16 = w1_16 + 65536;
  ushort* wq_16 = w2_16 + 65536;
  ushort* wk_16 = wq_16 + 65536;
  ushort* wv_16 = wk_16 + 65536;
  ushort* wo_16 = wv_16 + 65536;
  ushort* WtT1  = wo_16 + 65536;
  ushort* WtT2  = WtT1 + 512 * 1280;

  dim3 blk(256);
  mask_prep_kernel<<<dim3(64), blk, 0, stream>>>(msk, fmask);
  cast_f2b_kernel<<<dim3(4096), blk, 0, stream>>>(x, G0, (int)(ND / 4));
  cast_f2b_kernel<<<dim3(64), blk, 0, stream>>>(W1, w1_16, 16384);
  cast_f2b_kernel<<<dim3(64), blk, 0, stream>>>(W2, w2_16, 16384);
  cast_f2b_kernel<<<dim3(64), blk, 0, stream>>>(Wq, wq_16, 16384);
  cast_f2b_kernel<<<dim3(64), blk, 0, stream>>>(Wk, wk_16, 16384);
  cast_f2b_kernel<<<dim3(64), blk, 0, stream>>>(Wv, wv_16, 16384);
  cast_f2b_kernel<<<dim3(64), blk, 0, stream>>>(Wo, wo_16, 16384);
  conv_w_prep_kernel<<<dim3(2560), blk, 0, stream>>>(cW1, WtT1);
  conv_w_prep_kernel<<<dim3(2560), blk, 0, stream>>>(cW2, WtT2);
  qk_ext_fill_kernel<<<dim3(128), blk, 0, stream>>>(fmask, QE, KE);
  // spectral MLP
  gemm_mfma_kernel<1, 0, 1><<<dim3(256), blk, 0, stream>>>(
      G0, w1_16, b1, nullptr, nullptr, G1);
  gemm_mfma_kernel<1, 0, 2><<<dim3(256), blk, 0, stream>>>(
      G1, w2_16, b2, nullptr, F0, G0);
  // conv GLU x2
  conv_mfma_kernel<0><<<dim3(2, 128), blk, 0, stream>>>(
      G0, F0, WtT1, cb1, fmask, F1, G1);
  conv_mfma_kernel<1><<<dim3(2, 128), blk, 0, stream>>>(
      G1, F1, WtT2, cb2, fmask, F0, G0);
  // attention projections into QE/KE/VT layouts
  gemm_mfma_kernel<0, 0, 3><<<dim3(256), blk, 0, stream>>>(
      G0, wq_16, bq, nullptr, nullptr, QE);
  gemm_mfma_kernel<0, 0, 4><<<dim3(256), blk, 0, stream>>>(
      G0, wk_16, bk, nullptr, nullptr, KE);
  gemm_mfma_kernel<0, 0, 5><<<dim3(256), blk, 0, stream>>>(
      G0, wv_16, bv, nullptr, nullptr, VT);
  attn_mfma2_kernel<<<dim3(16, 32), blk, 0, stream>>>(QE, KE, VT, G1);
  // out-proj + residual
  gemm_mfma_kernel<0, 1, 0><<<dim3(256), blk, 0, stream>>>(
      G1, wo_16, bo, F0, F1, nullptr);
  // pool-then-project
  pool_prep_kernel<<<dim3(16), blk, 0, stream>>>(fmask, pooled, lenb);
  pool_kernel<<<dim3(32, 16), blk, 0, stream>>>(F1, fmask, pooled);
  final_kernel<<<dim3(16), blk, 0, stream>>>(pooled, lenb, Wf, bf, out);
}

// Round 5
// 360.280 us; speedup vs baseline: 3.7752x; 1.2824x over previous
//
#include <hip/hip_runtime.h>
#include <hip/hip_bf16.h>
#include <math.h>

// ============================================================================
// StylePredictor. Round 5: frag-major global layouts for attention K/V and
// conv weights (dense 1KB frag loads); in-lane GLU conv (2 blocks/CU);
// fused QKV dispatch; mega-prep kernel (23 -> 11 dispatches); fast mish.
// ============================================================================

#define DEV __device__ __forceinline__

static constexpr int B_ = 16, T_ = 1024, D_ = 256;
static constexpr int N_ = B_ * T_;

typedef __attribute__((ext_vector_type(8))) short bf16x8;
typedef __attribute__((ext_vector_type(16))) float floatx16;

DEV float sigmoidf_(float x) { return 1.f / (1.f + __expf(-x)); }
// mish(x) = x*tanh(softplus(x)) = x * t/(t+2), t = u*(u+2), u = e^x
DEV float mishf_(float x) {
  float u = __expf(fminf(x, 30.f));
  float t = u * (u + 2.f);
  return x * (t / (t + 2.f));
}
DEV ushort f2bf_(float x) {
  __hip_bfloat16 h = __float2bfloat16(x);
  return *(ushort*)&h;
}

// ---------------------------------------------------------------------------
// Mask prep + QE/KF bias chunks. Detects bool storage (int32/int8/fp32).
// fmask: 1.0 = masked (zero the frame). QE bias chunk = {1,0x15};
// KF chunk 8 = {mask?-6e4:0, 0x15}. grid 128 x 256 covers (bh,t) = 32768.
// ---------------------------------------------------------------------------
__global__ __launch_bounds__(256) void prep_mask_kernel(
    const unsigned* __restrict__ mraw, float* __restrict__ fmask,
    ushort* __restrict__ QE, ushort* __restrict__ KF) {
  int tid = threadIdx.x;
  int isByte = 0, isFloat = 0;
  for (int i = 0; i < 16; ++i) {
    unsigned v = mraw[tid * 16 + i];
    if (v == 0x3F800000u) isFloat = 1;
    else if (v > 1u) isByte = 1;
  }
  __shared__ int sByte, sFloat;
  if (tid == 0) { sByte = 0; sFloat = 0; }
  __syncthreads();
  if (isByte) atomicOr(&sByte, 1);
  if (isFloat) atomicOr(&sFloat, 1);
  __syncthreads();
  int mode = sFloat ? 2 : (sByte ? 1 : 0);
  int id = blockIdx.x * 256 + tid;       // bh*1024 + t
  int bh = id >> 10, t = id & 1023, b = bh >> 1;
  int gidx = b * 1024 + t;
  unsigned mv;
  if (mode == 1) mv = ((const unsigned char*)mraw)[gidx];
  else           mv = mraw[gidx];
  float fm = (mv != 0u) ? 1.f : 0.f;
  if ((bh & 1) == 0) fmask[gidx] = fm;
  // QE bias chunk (cols 128..143 of the 144-col row)
  size_t qb = (size_t)id * 144 + 128;
  QE[qb] = f2bf_(1.f);
#pragma unroll
  for (int j = 1; j < 16; ++j) QE[qb + j] = 0;
  // KF chunk 8 (frag-major)
  size_t kb = ((size_t)(bh * 32 + (t >> 5)) * 9 + 8) * 512 + (t & 31) * 16;
  KF[kb] = (fm != 0.f) ? f2bf_(-60000.f) : (ushort)0;
#pragma unroll
  for (int j = 1; j < 16; ++j) KF[kb + j] = 0;
}

// ---------------------------------------------------------------------------
// Mega-prep: x cast (blocks 0..4095), 6 weight casts (4096..4479),
// conv weights -> frag-major WtF (4480..9599).
// WtF frag = ((cot*5+tap)*8+c)*2+ks, element: co=cot*32+m31,
// cin=c*32+ks*16+half*8+j; src = cw[(co*256+cin)*5+tap].
// ---------------------------------------------------------------------------
__global__ __launch_bounds__(256) void prep_all_kernel(
    const float* __restrict__ x,
    const float* __restrict__ W1, const float* __restrict__ W2,
    const float* __restrict__ Wq, const float* __restrict__ Wk,
    const float* __restrict__ Wv, const float* __restrict__ Wo,
    const float* __restrict__ cW1, const float* __restrict__ cW2,
    ushort* __restrict__ G0, ushort* __restrict__ w1, ushort* __restrict__ w2,
    ushort* __restrict__ wqkv, ushort* __restrict__ wo,
    ushort* __restrict__ WtF1, ushort* __restrict__ WtF2) {
  int bid = blockIdx.x, tid = threadIdx.x;
  if (bid < 4096) {
    int i = bid * 256 + tid;
    float4 v = ((const float4*)x)[i];
    ushort4 u;
    u.x = f2bf_(v.x); u.y = f2bf_(v.y); u.z = f2bf_(v.z); u.w = f2bf_(v.w);
    ((ushort4*)G0)[i] = u;
  } else if (bid < 4480) {
    int i = (bid - 4096) * 256 + tid;  // 0..98303
    int widx = i >> 14, r = i & 16383;
    const float* src;
    ushort* dst;
    switch (widx) {
      case 0: src = W1; dst = w1; break;
      case 1: src = W2; dst = w2; break;
      case 2: src = Wq; dst = wqkv; break;
      case 3: src = Wk; dst = wqkv + 65536; break;
      case 4: src = Wv; dst = wqkv + 131072; break;
      default: src = Wo; dst = wo; break;
    }
    float4 v = ((const float4*)src)[r];
    ushort4 u;
    u.x = f2bf_(v.x); u.y = f2bf_(v.y); u.z = f2bf_(v.z); u.w = f2bf_(v.w);
    ((ushort4*)dst)[r] = u;
  } else {
    int idx = (bid - 4480) * 256 + tid;  // 0..1310719
    const float* cw = (idx < 655360) ? cW1 : cW2;
    ushort* dst = (idx < 655360) ? WtF1 : WtF2;
    int i = (idx < 655360) ? idx : idx - 655360;
    int j = i & 7, half = (i >> 3) & 1, m31 = (i >> 4) & 31;
    int frag = i >> 9;
    int ks = frag & 1, c = (frag >> 1) & 7, tap = (frag >> 4) % 5,
        cot = frag / 80;
    int co = cot * 32 + m31;
    int cin = c * 32 + ks * 16 + half * 8 + j;
    dst[i] = f2bf_(cw[(size_t)(co * 256 + cin) * 5 + tap]);
  }
}

// ---------------------------------------------------------------------------
// bf16 MFMA GEMM: C = act(A @ W^T + bias) [+resid]. Block 64 rows x 256 cols,
// 4 waves (64x64 each, 2x2 32x32 tiles). A via LDS (stride 40: 16B-aligned
// b128 frag reads, conflict-free); B direct from global. OMODE: 0=f32,
// 1=bf16, 2=both. 32x32x16 layouts: A/B [m|n=lane&31][k=(lane>>5)*8+j];
// C/D col=lane&31, row=(reg&3)+8*(reg>>2)+4*(lane>>5).
// ---------------------------------------------------------------------------
template <int ACT, int RESID, int OMODE>
__global__ __launch_bounds__(256, 2) void gemm_mfma_kernel(
    const ushort* __restrict__ A16, const ushort* __restrict__ W16,
    const float* __restrict__ bias, const float* __restrict__ resid,
    float* __restrict__ outf, ushort* __restrict__ outb) {
  __shared__ __align__(16) ushort As[2][64 * 40];
  int tid = threadIdx.x;
  int w = tid >> 6, lane = tid & 63;
  int m31 = lane & 31, half = lane >> 5;
  int n0 = blockIdx.x * 64;

  floatx16 acc[2][2];
#pragma unroll
  for (int a = 0; a < 2; ++a)
#pragma unroll
    for (int b = 0; b < 2; ++b)
#pragma unroll
      for (int i = 0; i < 16; ++i) acc[a][b][i] = 0.f;

#pragma unroll
  for (int it = 0; it < 2; ++it) {
    int i = tid + it * 256;
    int row = i >> 3, part = i & 7;
    *(uint2*)&As[0][row * 40 + part * 4] =
        *(const uint2*)&A16[(size_t)(n0 + row) * 256 + part * 4];
  }
  bf16x8 bn[2][2];
#pragma unroll
  for (int ks = 0; ks < 2; ++ks)
#pragma unroll
    for (int ct = 0; ct < 2; ++ct)
      bn[ks][ct] = *(const bf16x8*)&W16[(size_t)(w * 64 + ct * 32 + m31) * 256 +
                                        ks * 16 + half * 8];

  for (int c = 0; c < 8; ++c) {
    __syncthreads();
    if (c < 7) {
      int k0 = (c + 1) * 32;
#pragma unroll
      for (int it = 0; it < 2; ++it) {
        int i = tid + it * 256;
        int row = i >> 3, part = i & 7;
        *(uint2*)&As[(c + 1) & 1][row * 40 + part * 4] =
            *(const uint2*)&A16[(size_t)(n0 + row) * 256 + k0 + part * 4];
      }
    }
    bf16x8 bc[2][2];
#pragma unroll
    for (int ks = 0; ks < 2; ++ks)
#pragma unroll
      for (int ct = 0; ct < 2; ++ct) bc[ks][ct] = bn[ks][ct];
    if (c < 7) {
      int k0 = (c + 1) * 32;
#pragma unroll
      for (int ks = 0; ks < 2; ++ks)
#pragma unroll
        for (int ct = 0; ct < 2; ++ct)
          bn[ks][ct] = *(const bf16x8*)&W16[
              (size_t)(w * 64 + ct * 32 + m31) * 256 + k0 + ks * 16 + half * 8];
    }
    const ushort* ab = As[c & 1];
#pragma unroll
    for (int ks = 0; ks < 2; ++ks) {
      bf16x8 af[2];
#pragma unroll
      for (int rt = 0; rt < 2; ++rt)
        af[rt] = *(const bf16x8*)&ab[(rt * 32 + m31) * 40 + ks * 16 + half * 8];
#pragma unroll
      for (int rt = 0; rt < 2; ++rt)
#pragma unroll
        for (int ct = 0; ct < 2; ++ct)
          acc[rt][ct] = __builtin_amdgcn_mfma_f32_32x32x16_bf16(
              af[rt], bc[ks][ct], acc[rt][ct], 0, 0, 0);
    }
  }
#pragma unroll
  for (int ct = 0; ct < 2; ++ct) {
    int col = w * 64 + ct * 32 + m31;
    float bv = bias[col];
#pragma unroll
    for (int rt = 0; rt < 2; ++rt) {
#pragma unroll
      for (int reg = 0; reg < 16; ++reg) {
        int row = n0 + rt * 32 + (reg & 3) + 8 * (reg >> 2) + 4 * half;
        float v = acc[rt][ct][reg] + bv;
        if (ACT == 1) v = mishf_(v);
        if (RESID) v += resid[(size_t)row * 256 + col];
        if (OMODE == 0) {
          outf[(size_t)row * 256 + col] = v;
        } else if (OMODE == 1) {
          outb[(size_t)row * 256 + col] = f2bf_(v);
        } else {
          outf[(size_t)row * 256 + col] = v;
          outb[(size_t)row * 256 + col] = f2bf_(v);
        }
      }
    }
  }
}

// ---------------------------------------------------------------------------
// Fused QKV projection. grid (256, 3): by 0=Q->QE (x1/16, [bh][t][144]),
// 1=K->KF frag-major, 2=V->VF frag-major. Same GEMM body as above.
// KF: ((bh*32+(t>>5))*9 + dk>>4)*512 + (t&31)*16 + ((dk>>3)&1)*8 + (dk&7)
// VF: ((bh*16+(t>>6))*16 + ((t>>4)&3)*4 + dv>>5)*512 + (dv&31)*16
//      + ((t>>3)&1)*8 + (t&7)
// ---------------------------------------------------------------------------
__global__ __launch_bounds__(256, 2) void qkv_mfma_kernel(
    const ushort* __restrict__ A16, const ushort* __restrict__ wqkv,
    const float* __restrict__ bq, const float* __restrict__ bk,
    const float* __restrict__ bv,
    ushort* __restrict__ QE, ushort* __restrict__ KF, ushort* __restrict__ VF) {
  __shared__ __align__(16) ushort As[2][64 * 40];
  int tid = threadIdx.x;
  int w = tid >> 6, lane = tid & 63;
  int m31 = lane & 31, half = lane >> 5;
  int n0 = blockIdx.x * 64;
  int by = blockIdx.y;
  const ushort* W16 = wqkv + (size_t)by * 65536;
  const float* bias = (by == 0) ? bq : (by == 1) ? bk : bv;

  floatx16 acc[2][2];
#pragma unroll
  for (int a = 0; a < 2; ++a)
#pragma unroll
    for (int b = 0; b < 2; ++b)
#pragma unroll
      for (int i = 0; i < 16; ++i) acc[a][b][i] = 0.f;

#pragma unroll
  for (int it = 0; it < 2; ++it) {
    int i = tid + it * 256;
    int row = i >> 3, part = i & 7;
    *(uint2*)&As[0][row * 40 + part * 4] =
        *(const uint2*)&A16[(size_t)(n0 + row) * 256 + part * 4];
  }
  bf16x8 bn[2][2];
#pragma unroll
  for (int ks = 0; ks < 2; ++ks)
#pragma unroll
    for (int ct = 0; ct < 2; ++ct)
      bn[ks][ct] = *(const bf16x8*)&W16[(size_t)(w * 64 + ct * 32 + m31) * 256 +
                                        ks * 16 + half * 8];
  for (int c = 0; c < 8; ++c) {
    __syncthreads();
    if (c < 7) {
      int k0 = (c + 1) * 32;
#pragma unroll
      for (int it = 0; it < 2; ++it) {
        int i = tid + it * 256;
        int row = i >> 3, part = i & 7;
        *(uint2*)&As[(c + 1) & 1][row * 40 + part * 4] =
            *(const uint2*)&A16[(size_t)(n0 + row) * 256 + k0 + part * 4];
      }
    }
    bf16x8 bc[2][2];
#pragma unroll
    for (int ks = 0; ks < 2; ++ks)
#pragma unroll
      for (int ct = 0; ct < 2; ++ct) bc[ks][ct] = bn[ks][ct];
    if (c < 7) {
      int k0 = (c + 1) * 32;
#pragma unroll
      for (int ks = 0; ks < 2; ++ks)
#pragma unroll
        for (int ct = 0; ct < 2; ++ct)
          bn[ks][ct] = *(const bf16x8*)&W16[
              (size_t)(w * 64 + ct * 32 + m31) * 256 + k0 + ks * 16 + half * 8];
    }
    const ushort* ab = As[c & 1];
#pragma unroll
    for (int ks = 0; ks < 2; ++ks) {
      bf16x8 af[2];
#pragma unroll
      for (int rt = 0; rt < 2; ++rt)
        af[rt] = *(const bf16x8*)&ab[(rt * 32 + m31) * 40 + ks * 16 + half * 8];
#pragma unroll
      for (int rt = 0; rt < 2; ++rt)
#pragma unroll
        for (int ct = 0; ct < 2; ++ct)
          acc[rt][ct] = __builtin_amdgcn_mfma_f32_32x32x16_bf16(
              af[rt], bc[ks][ct], acc[rt][ct], 0, 0, 0);
    }
  }
  int b = n0 >> 10;
#pragma unroll
  for (int ct = 0; ct < 2; ++ct) {
    int col = w * 64 + ct * 32 + m31;
    float bvv = bias[col];
    int h = col >> 7, d127 = col & 127;
    int bh = b * 2 + h;
    if (by == 2) {  // VF, ushort4 stores (t-contiguous within j-octet)
      int ctv = d127 >> 5, m31v = d127 & 31;
#pragma unroll
      for (int rt = 0; rt < 2; ++rt)
#pragma unroll
        for (int rg = 0; rg < 4; ++rg) {
          int t0 = (n0 & 1023) + rt * 32 + 8 * rg + 4 * half;
          ushort4 u;
          u.x = f2bf_(acc[rt][ct][rg * 4 + 0] + bvv);
          u.y = f2bf_(acc[rt][ct][rg * 4 + 1] + bvv);
          u.z = f2bf_(acc[rt][ct][rg * 4 + 2] + bvv);
          u.w = f2bf_(acc[rt][ct][rg * 4 + 3] + bvv);
          size_t addr = ((size_t)(bh * 16 + (t0 >> 6)) * 16 +
                         ((t0 >> 4) & 3) * 4 + ctv) * 512 +
                        m31v * 16 + ((t0 >> 3) & 1) * 8 + (t0 & 7);
          *(ushort4*)&VF[addr] = u;
        }
    } else {
#pragma unroll
      for (int rt = 0; rt < 2; ++rt)
#pragma unroll
        for (int reg = 0; reg < 16; ++reg) {
          int t = (n0 & 1023) + rt * 32 + (reg & 3) + 8 * (reg >> 2) + 4 * half;
          float v = acc[rt][ct][reg] + bvv;
          if (by == 0) {
            QE[((size_t)(bh * 1024 + t)) * 144 + d127] = f2bf_(v * 0.0625f);
          } else {
            size_t addr = ((size_t)(bh * 32 + (t >> 5)) * 9 + (d127 >> 4)) * 512 +
                          (t & 31) * 16 + ((d127 >> 3) & 1) * 8 + (d127 & 7);
            KF[addr] = f2bf_(v);
          }
        }
    }
  }
}

// ---------------------------------------------------------------------------
// Conv1dGLU bf16 MFMA, in-lane GLU. Block = 128 rows x (64 a-cols + their
// 64 g-cols); grid (4, 128) = 512 blocks (2/CU). Wave (wr,wc) = 64 rows x
// (32a + 32g): acc 2rt x 2ct. A: LDS 132 rows stride 40 (16B-aligned b128,
// conflict-free), dbuf; B: dense frag-major WtF from global, one-tap-ahead
// prefetch. GLU pairing is lane-local (a-col and g-col in the same lane).
// ---------------------------------------------------------------------------
template <int DO_MASK>
__global__ __launch_bounds__(256, 2) void conv_mfma_kernel(
    const ushort* __restrict__ H16, const float* __restrict__ Hf,
    const ushort* __restrict__ WtF, const float* __restrict__ cb,
    const float* __restrict__ fmask, float* __restrict__ outf,
    ushort* __restrict__ outb) {
  __shared__ __align__(16) ushort As[2][132 * 40];
  int tid = threadIdx.x;
  int w = tid >> 6, lane = tid & 63;
  int m31 = lane & 31, half = lane >> 5;
  int wr = w >> 1, wc = w & 1;
  int cg = blockIdx.x;                   // 0..3 : 64 a-cols each
  int n0 = blockIdx.y * 128;
  int tbase = n0 & 1023;
  int acol = cg * 64 + wc * 32;          // +m31
  int cotA = cg * 2 + wc, cotG = 8 + cg * 2 + wc;

  floatx16 acc[2][2];
#pragma unroll
  for (int a = 0; a < 2; ++a)
#pragma unroll
    for (int b = 0; b < 2; ++b)
#pragma unroll
      for (int i = 0; i < 16; ++i) acc[a][b][i] = 0.f;

  for (int i = tid; i < 1056; i += 256) {
    int row = i >> 3, part = i & 7;
    int t = tbase + row - 2;
    uint2 v = make_uint2(0u, 0u);
    if ((unsigned)t < 1024u)
      v = *(const uint2*)&H16[(size_t)(n0 + row - 2) * 256 + part * 4];
    *(uint2*)&As[0][row * 40 + part * 4] = v;
  }
  bf16x8 bn[2][2];
#pragma unroll
  for (int ks = 0; ks < 2; ++ks) {
    bn[ks][0] = *(const bf16x8*)&WtF[(size_t)(((cotA * 5 + 0) * 8 + 0) * 2 + ks) * 512 +
                                     m31 * 16 + half * 8];
    bn[ks][1] = *(const bf16x8*)&WtF[(size_t)(((cotG * 5 + 0) * 8 + 0) * 2 + ks) * 512 +
                                     m31 * 16 + half * 8];
  }

  for (int c = 0; c < 8; ++c) {
    __syncthreads();
    if (c < 7) {
      int k0 = (c + 1) * 32;
      for (int i = tid; i < 1056; i += 256) {
        int row = i >> 3, part = i & 7;
        int t = tbase + row - 2;
        uint2 v = make_uint2(0u, 0u);
        if ((unsigned)t < 1024u)
          v = *(const uint2*)&H16[(size_t)(n0 + row - 2) * 256 + k0 + part * 4];
        *(uint2*)&As[(c + 1) & 1][row * 40 + part * 4] = v;
      }
    }
    const ushort* ab = As[c & 1];
#pragma unroll
    for (int tap = 0; tap < 5; ++tap) {
      bf16x8 bc[2][2];
#pragma unroll
      for (int ks = 0; ks < 2; ++ks)
#pragma unroll
        for (int ct = 0; ct < 2; ++ct) bc[ks][ct] = bn[ks][ct];
      int pc = c, pt = tap + 1;
      if (pt == 5) { pc = c + 1; pt = 0; }
      if (pc < 8) {
#pragma unroll
        for (int ks = 0; ks < 2; ++ks) {
          bn[ks][0] = *(const bf16x8*)&WtF[
              (size_t)(((cotA * 5 + pt) * 8 + pc) * 2 + ks) * 512 + m31 * 16 + half * 8];
          bn[ks][1] = *(const bf16x8*)&WtF[
              (size_t)(((cotG * 5 + pt) * 8 + pc) * 2 + ks) * 512 + m31 * 16 + half * 8];
        }
      }
#pragma unroll
      for (int ks = 0; ks < 2; ++ks) {
        bf16x8 af[2];
#pragma unroll
        for (int rt = 0; rt < 2; ++rt)
          af[rt] = *(const bf16x8*)&ab[(wr * 64 + rt * 32 + m31 + tap) * 40 +
                                       ks * 16 + half * 8];
#pragma unroll
        for (int rt = 0; rt < 2; ++rt)
#pragma unroll
          for (int ct = 0; ct < 2; ++ct)
            acc[rt][ct] = __builtin_amdgcn_mfma_f32_32x32x16_bf16(
                af[rt], bc[ks][ct], acc[rt][ct], 0, 0, 0);
      }
    }
  }
  // in-lane GLU epilogue
  int col = acol + m31;
  float ba = cb[col], bg = cb[256 + col];
#pragma unroll
  for (int rt = 0; rt < 2; ++rt) {
#pragma unroll
    for (int reg = 0; reg < 16; ++reg) {
      int brow = wr * 64 + rt * 32 + (reg & 3) + 8 * (reg >> 2) + 4 * half;
      int grow = n0 + brow;
      float a = acc[rt][0][reg] + ba;
      float g = acc[rt][1][reg] + bg;
      float v = Hf[(size_t)grow * 256 + col] + a * sigmoidf_(g);
      if (DO_MASK) {
        if (fmask[grow] != 0.f) v = 0.f;
      }
      outf[(size_t)grow * 256 + col] = v;
      outb[(size_t)grow * 256 + col] = f2bf_(v);
    }
  }
}

// ---------------------------------------------------------------------------
// LDS-free bf16 MFMA flash attention with frag-major K/V (dense 1KB loads).
// QE [bh][t][144] (Q/16 + bias col); KF/VF frag-major; O bf16 [N,256].
// Block = (b,h) x 64 q; wave (qt,kh) = 32 q x 512 keys. V-frags for s2=0,1
// prefetched before the softmax chain. kh-halves merged through LDS.
// ---------------------------------------------------------------------------
__global__ __launch_bounds__(256, 2) void attn_mfma2_kernel(
    const ushort* __restrict__ QE, const ushort* __restrict__ KF,
    const ushort* __restrict__ VF, ushort* __restrict__ O) {
  __shared__ float Op[2][128][33];
  __shared__ float Ml[2][2][32];
  int tid = threadIdx.x;
  int w = tid >> 6, lane = tid & 63;
  int m31 = lane & 31, half = lane >> 5;
  int qt = w & 1, kh = w >> 1;
  int bh = blockIdx.y;
  int q0 = blockIdx.x * 64 + qt * 32;
  int lpos = m31 * 16 + half * 8;

  bf16x8 qe[9];
  {
    size_t qrow = ((size_t)(bh * 1024 + q0 + m31)) * 144;
#pragma unroll
    for (int c = 0; c < 9; ++c)
      qe[c] = *(const bf16x8*)&QE[qrow + c * 16 + half * 8];
  }
  floatx16 oacc[4];
#pragma unroll
  for (int ct = 0; ct < 4; ++ct)
#pragma unroll
    for (int i = 0; i < 16; ++i) oacc[ct][i] = 0.f;
  float mi = -1e30f, li = 0.f;

  for (int it = 0; it < 8; ++it) {
    int ktb = kh * 512 + it * 64;
    int kfrag = (bh * 32 + (ktb >> 5)) * 9;
    int vtile = (bh * 16 + (ktb >> 6)) * 16;
    floatx16 s0, s1;
#pragma unroll
    for (int i = 0; i < 16; ++i) { s0[i] = 0.f; s1[i] = 0.f; }
#pragma unroll
    for (int c = 0; c < 9; ++c) {
      bf16x8 kf0 = *(const bf16x8*)&KF[(size_t)(kfrag + c) * 512 + lpos];
      bf16x8 kf1 = *(const bf16x8*)&KF[(size_t)(kfrag + 9 + c) * 512 + lpos];
      s0 = __builtin_amdgcn_mfma_f32_32x32x16_bf16(kf0, qe[c], s0, 0, 0, 0);
      s1 = __builtin_amdgcn_mfma_f32_32x32x16_bf16(kf1, qe[c], s1, 0, 0, 0);
    }
    // prefetch V-frags s2=0,1 (overlaps the softmax chain)
    bf16x8 vfr[2][4];
#pragma unroll
    for (int s2 = 0; s2 < 2; ++s2)
#pragma unroll
      for (int ct = 0; ct < 4; ++ct)
        vfr[s2][ct] = *(const bf16x8*)&VF[(size_t)(vtile + s2 * 4 + ct) * 512 + lpos];
    // softmax (lane-local q = m31; xor-32 partner holds other 16 kt rows)
    float mloc = s0[0];
#pragma unroll
    for (int r = 1; r < 16; ++r) mloc = fmaxf(mloc, s0[r]);
#pragma unroll
    for (int r = 0; r < 16; ++r) mloc = fmaxf(mloc, s1[r]);
    float mt = fmaxf(mloc, __shfl_xor(mloc, 32));
    float mnew = fmaxf(mi, mt);
    float alpha = __expf(mi - mnew);
    bool dead = (mnew <= -3.0e4f);
    float sum = 0.f;
#pragma unroll
    for (int r = 0; r < 16; ++r) {
      float v0 = dead ? 0.f : __expf(s0[r] - mnew);
      float v1 = dead ? 0.f : __expf(s1[r] - mnew);
      s0[r] = v0; s1[r] = v1;
      sum += v0 + v1;
    }
    sum += __shfl_xor(sum, 32);
    li = li * alpha + sum;
    mi = mnew;
#pragma unroll
    for (int ct = 0; ct < 4; ++ct)
#pragma unroll
      for (int i = 0; i < 16; ++i) oacc[ct][i] *= alpha;
    // xor-32 exchange -> P^T B-frags [n=q][k=kt]
    bf16x8 pf[4];
#pragma unroll
    for (int sub = 0; sub < 2; ++sub) {
      float tx[16];
#pragma unroll
      for (int r = 0; r < 16; ++r)
        tx[r] = __shfl_xor(sub == 0 ? s0[r] : s1[r], 32);
#pragma unroll
      for (int s = 0; s < 2; ++s) {
        union { bf16x8 v; ushort u[8]; } pk;
#pragma unroll
        for (int j = 0; j < 8; ++j) {
          int base = s * 8;
          float own = (sub == 0) ? s0[base + j] : s1[base + j];
          float lo = (j < 4) ? own : tx[base + j - 4];
          float hi = (j < 4) ? tx[base + 4 + j] : own;
          pk.u[j] = f2bf_(half ? hi : lo);
        }
        pf[sub * 2 + s] = pk.v;
      }
    }
    // O^T += VF . P^T
#pragma unroll
    for (int s2 = 0; s2 < 4; ++s2)
#pragma unroll
      for (int ct = 0; ct < 4; ++ct) {
        bf16x8 vf = (s2 < 2) ? vfr[s2][ct]
                  : *(const bf16x8*)&VF[(size_t)(vtile + s2 * 4 + ct) * 512 + lpos];
        oacc[ct] = __builtin_amdgcn_mfma_f32_32x32x16_bf16(
            vf, pf[s2], oacc[ct], 0, 0, 0);
      }
  }
  // merge key-halves
  if (kh == 1) {
#pragma unroll
    for (int ct = 0; ct < 4; ++ct)
#pragma unroll
      for (int r = 0; r < 16; ++r) {
        int dv = ct * 32 + (r & 3) + 8 * (r >> 2) + 4 * half;
        Op[qt][dv][m31] = oacc[ct][r];
      }
    if (half == 0) { Ml[qt][0][m31] = mi; Ml[qt][1][m31] = li; }
  }
  __syncthreads();
  if (kh == 0) {
    float mB = Ml[qt][0][m31], lB = Ml[qt][1][m31];
    float m = fmaxf(mi, mB);
    float aA = __expf(mi - m), aB = __expf(mB - m);
    float l = li * aA + lB * aB;
    float inv = (l > 0.f) ? 1.f / l : 0.f;
    int b = bh >> 1, h = bh & 1;
    size_t rowbase = (size_t)(b * 1024 + q0 + m31) * 256 + h * 128;
#pragma unroll
    for (int ct = 0; ct < 4; ++ct)
#pragma unroll
      for (int rg = 0; rg < 4; ++rg) {
        int dv0 = ct * 32 + 8 * rg + 4 * half;
        ushort4 u;
        u.x = f2bf_((oacc[ct][rg * 4 + 0] * aA + Op[qt][dv0 + 0][m31] * aB) * inv);
        u.y = f2bf_((oacc[ct][rg * 4 + 1] * aA + Op[qt][dv0 + 1][m31] * aB) * inv);
        u.z = f2bf_((oacc[ct][rg * 4 + 2] * aA + Op[qt][dv0 + 2][m31] * aB) * inv);
        u.w = f2bf_((oacc[ct][rg * 4 + 3] * aA + Op[qt][dv0 + 3][m31] * aB) * inv);
        *(ushort4*)&O[rowbase + dv0] = u;
      }
  }
}

// ---------------------------------------------------------------------------
// Pool (partials) + final projection.
// ---------------------------------------------------------------------------
__global__ __launch_bounds__(256) void pool_part_kernel(
    const float* __restrict__ h5, const float* __restrict__ fmask,
    float* __restrict__ pooled8) {
  int ch = blockIdx.x, b = blockIdx.y, d = threadIdx.x;
  float s = 0.f;
  for (int i = 0; i < 128; ++i) {
    int t = ch * 128 + i;
    if (fmask[b * 1024 + t] == 0.f)
      s += h5[((size_t)b * 1024 + t) * 256 + d];
  }
  pooled8[(b * 8 + ch) * 256 + d] = s;
}

__global__ __launch_bounds__(256) void final_kernel(
    const float* __restrict__ pooled8, const float* __restrict__ fmask,
    const float* __restrict__ Wf, const float* __restrict__ bf,
    float* __restrict__ out) {
  int b = blockIdx.x, j = threadIdx.x;
  __shared__ __align__(16) float p[256];
  __shared__ float red[256];
  float s = 0.f;
  for (int ch = 0; ch < 8; ++ch) s += pooled8[(b * 8 + ch) * 256 + j];
  p[j] = s;
  float c = 0.f;
  for (int i = 0; i < 4; ++i)
    c += (fmask[b * 1024 + i * 256 + j] == 0.f) ? 1.f : 0.f;
  red[j] = c;
  __syncthreads();
  for (int st = 128; st > 0; st >>= 1) {
    if (j < st) red[j] += red[j + st];
    __syncthreads();
  }
  float len = red[0];
  const float* wrow = Wf + (size_t)j * 256;
  float acc = 0.f;
  for (int d4 = 0; d4 < 64; ++d4) {
    float4 wv = ((const float4*)wrow)[d4];
    float4 pv = ((const float4*)p)[d4];
    acc += wv.x * pv.x + wv.y * pv.y + wv.z * pv.z + wv.w * pv.w;
  }
  float inv = (len > 0.f) ? 1.f / len : 0.f;
  out[b * 256 + j] = acc * inv + bf[j];
}

// ---------------------------------------------------------------------------
extern "C" void kernel_launch(void* const* d_in, const int* in_sizes, int n_in,
                              void* d_out, int out_size, void* d_ws, size_t ws_size,
                              hipStream_t stream) {
  const float* x      = (const float*)d_in[0];
  const unsigned* msk = (const unsigned*)d_in[1];
  const float* W1 = (const float*)d_in[2];
  const float* b1 = (const float*)d_in[3];
  const float* W2 = (const float*)d_in[4];
  const float* b2 = (const float*)d_in[5];
  const float* cW1 = (const float*)d_in[6];
  const float* cb1 = (const float*)d_in[7];
  const float* cW2 = (const float*)d_in[8];
  const float* cb2 = (const float*)d_in[9];
  const float* Wq = (const float*)d_in[10];
  const float* bq = (const float*)d_in[11];
  const float* Wk = (const float*)d_in[12];
  const float* bk = (const float*)d_in[13];
  const float* Wv = (const float*)d_in[14];
  const float* bv = (const float*)d_in[15];
  const float* Wo = (const float*)d_in[16];
  const float* bo = (const float*)d_in[17];
  const float* Wf = (const float*)d_in[18];
  const float* bf = (const float*)d_in[19];
  float* out = (float*)d_out;

  float* ws = (float*)d_ws;
  size_t ND = (size_t)N_ * D_;  // 4194304
  float* F0      = ws;
  float* F1      = F0 + ND;
  float* fmask   = F1 + ND;
  float* pooled8 = fmask + N_;           // [16*8*256]
  ushort* G0 = (ushort*)(pooled8 + 16 * 8 * 256);
  ushort* G1 = G0 + ND;
  ushort* QE = G1 + ND;                  // [32*1024*144]
  ushort* KF = QE + (size_t)32 * 1024 * 144;   // [32*32*9*512]
  ushort* VF = KF + (size_t)32 * 32 * 9 * 512; // [32*16*16*512]
  ushort* w1_16 = VF + (size_t)32 * 16 * 16 * 512;
  ushort* w2_16 = w1_16 + 65536;
  ushort* wo_16 = w2_16 + 65536;
  ushort* wqkv  = wo_16 + 65536;         // 3 x 65536
  ushort* WtF1  = wqkv + 3 * 65536;      // [655360]
  ushort* WtF2  = WtF1 + 655360;

  dim3 blk(256);
  prep_mask_kernel<<<dim3(128), blk, 0, stream>>>(msk, fmask, QE, KF);
  prep_all_kernel<<<dim3(9600), blk, 0, stream>>>(
      x, W1, W2, Wq, Wk, Wv, Wo, cW1, cW2,
      G0, w1_16, w2_16, wqkv, wo_16, WtF1, WtF2);
  // spectral MLP
  gemm_mfma_kernel<1, 0, 1><<<dim3(256), blk, 0, stream>>>(
      G0, w1_16, b1, nullptr, nullptr, G1);
  gemm_mfma_kernel<1, 0, 2><<<dim3(256), blk, 0, stream>>>(
      G1, w2_16, b2, nullptr, F0, G0);
  // conv GLU x2 (second fuses mask-zeroing)
  conv_mfma_kernel<0><<<dim3(4, 128), blk, 0, stream>>>(
      G0, F0, WtF1, cb1, fmask, F1, G1);
  conv_mfma_kernel<1><<<dim3(4, 128), blk, 0, stream>>>(
      G1, F1, WtF2, cb2, fmask, F0, G0);
  // fused QKV into QE/KF/VF layouts
  qkv_mfma_kernel<<<dim3(256, 3), blk, 0, stream>>>(
      G0, wqkv, bq, bk, bv, QE, KF, VF);
  attn_mfma2_kernel<<<dim3(16, 32), blk, 0, stream>>>(QE, KF, VF, G1);
  // out-proj + residual
  gemm_mfma_kernel<0, 1, 0><<<dim3(256), blk, 0, stream>>>(
      G1, wo_16, bo, F0, F1, nullptr);
  // pool-then-project
  pool_part_kernel<<<dim3(8, 16), blk, 0, stream>>>(F1, fmask, pooled8);
  final_kernel<<<dim3(16), blk, 0, stream>>>(pooled8, fmask, Wf, bf, out);
}

// Round 6
// 327.554 us; speedup vs baseline: 4.1524x; 1.0999x over previous
//
#include <hip/hip_runtime.h>
#include <hip/hip_bf16.h>
#include <math.h>

// ============================================================================
// StylePredictor. Round 6: XCD-aware attention grid (bh-major block IDs so
// q-blocks sharing K/V land on one XCD -> L2-resident K/V); pooling fused
// into out-proj epilogue (h5 never materialized); mask prep merged into the
// mega-prep kernel (9 dispatches).
// ============================================================================

#define DEV __device__ __forceinline__

static constexpr int B_ = 16, T_ = 1024, D_ = 256;
static constexpr int N_ = B_ * T_;

typedef __attribute__((ext_vector_type(8))) short bf16x8;
typedef __attribute__((ext_vector_type(16))) float floatx16;

DEV float sigmoidf_(float x) { return 1.f / (1.f + __expf(-x)); }
// mish(x) = x*tanh(softplus(x)) = x * t/(t+2), t = u*(u+2), u = e^x
DEV float mishf_(float x) {
  float u = __expf(fminf(x, 30.f));
  float t = u * (u + 2.f);
  return x * (t / (t + 2.f));
}
DEV ushort f2bf_(float x) {
  __hip_bfloat16 h = __float2bfloat16(x);
  return *(ushort*)&h;
}

// ---------------------------------------------------------------------------
// Mega-prep: x cast (blocks 0..4095), 6 weight casts (4096..4479),
// conv weights -> frag-major WtF (4480..9599), mask + QE/KF bias chunks +
// pooled zero-init (9600..9727).
// ---------------------------------------------------------------------------
__global__ __launch_bounds__(256) void prep_all_kernel(
    const float* __restrict__ x, const unsigned* __restrict__ mraw,
    const float* __restrict__ W1, const float* __restrict__ W2,
    const float* __restrict__ Wq, const float* __restrict__ Wk,
    const float* __restrict__ Wv, const float* __restrict__ Wo,
    const float* __restrict__ cW1, const float* __restrict__ cW2,
    ushort* __restrict__ G0, ushort* __restrict__ w1, ushort* __restrict__ w2,
    ushort* __restrict__ wqkv, ushort* __restrict__ wo,
    ushort* __restrict__ WtF1, ushort* __restrict__ WtF2,
    float* __restrict__ fmask, ushort* __restrict__ QE,
    ushort* __restrict__ KF, float* __restrict__ pooled) {
  int bid = blockIdx.x, tid = threadIdx.x;
  if (bid < 4096) {
    int i = bid * 256 + tid;
    float4 v = ((const float4*)x)[i];
    ushort4 u;
    u.x = f2bf_(v.x); u.y = f2bf_(v.y); u.z = f2bf_(v.z); u.w = f2bf_(v.w);
    ((ushort4*)G0)[i] = u;
  } else if (bid < 4480) {
    int i = (bid - 4096) * 256 + tid;  // 0..98303
    int widx = i >> 14, r = i & 16383;
    const float* src;
    ushort* dst;
    switch (widx) {
      case 0: src = W1; dst = w1; break;
      case 1: src = W2; dst = w2; break;
      case 2: src = Wq; dst = wqkv; break;
      case 3: src = Wk; dst = wqkv + 65536; break;
      case 4: src = Wv; dst = wqkv + 131072; break;
      default: src = Wo; dst = wo; break;
    }
    float4 v = ((const float4*)src)[r];
    ushort4 u;
    u.x = f2bf_(v.x); u.y = f2bf_(v.y); u.z = f2bf_(v.z); u.w = f2bf_(v.w);
    ((ushort4*)dst)[r] = u;
  } else if (bid < 9600) {
    int idx = (bid - 4480) * 256 + tid;  // 0..1310719
    const float* cw = (idx < 655360) ? cW1 : cW2;
    ushort* dst = (idx < 655360) ? WtF1 : WtF2;
    int i = (idx < 655360) ? idx : idx - 655360;
    int j = i & 7, half = (i >> 3) & 1, m31 = (i >> 4) & 31;
    int frag = i >> 9;
    int ks = frag & 1, c = (frag >> 1) & 7, tap = (frag >> 4) % 5,
        cot = frag / 80;
    int co = cot * 32 + m31;
    int cin = c * 32 + ks * 16 + half * 8 + j;
    dst[i] = f2bf_(cw[(size_t)(co * 256 + cin) * 5 + tap]);
  } else {
    // mask detection + fmask + QE/KF bias chunks + pooled zero
    int isByte = 0, isFloat = 0;
    for (int i = 0; i < 16; ++i) {
      unsigned v = mraw[tid * 16 + i];
      if (v == 0x3F800000u) isFloat = 1;
      else if (v > 1u) isByte = 1;
    }
    __shared__ int sByte, sFloat;
    if (tid == 0) { sByte = 0; sFloat = 0; }
    __syncthreads();
    if (isByte) atomicOr(&sByte, 1);
    if (isFloat) atomicOr(&sFloat, 1);
    __syncthreads();
    int mode = sFloat ? 2 : (sByte ? 1 : 0);
    int mb = bid - 9600;                 // 0..127
    int id = mb * 256 + tid;             // bh*1024 + t
    int bh = id >> 10, t = id & 1023, b = bh >> 1;
    int gidx = b * 1024 + t;
    unsigned mv;
    if (mode == 1) mv = ((const unsigned char*)mraw)[gidx];
    else           mv = mraw[gidx];
    float fm = (mv != 0u) ? 1.f : 0.f;
    if ((bh & 1) == 0) fmask[gidx] = fm;
    if (mb < 16) pooled[mb * 256 + tid] = 0.f;
    // QE bias chunk (cols 128..143 of the 144-col row)
    size_t qb = (size_t)id * 144 + 128;
    QE[qb] = f2bf_(1.f);
#pragma unroll
    for (int j = 1; j < 16; ++j) QE[qb + j] = 0;
    // KF chunk 8 (frag-major)
    size_t kb = ((size_t)(bh * 32 + (t >> 5)) * 9 + 8) * 512 + (t & 31) * 16;
    KF[kb] = (fm != 0.f) ? f2bf_(-60000.f) : (ushort)0;
#pragma unroll
    for (int j = 1; j < 16; ++j) KF[kb + j] = 0;
  }
}

// ---------------------------------------------------------------------------
// bf16 MFMA GEMM: C = act(A @ W^T + bias) [+resid]. Block 64 rows x 256 cols,
// 4 waves (64x64 each, 2x2 32x32 tiles). A via LDS (stride 40, conflict-
// free b128 frags); B direct from global. OMODE: 0=f32, 1=bf16, 2=both,
// 3=masked-pool only (atomicAdd partial sums into pooled, no store).
// 32x32x16 layouts: A/B [m|n=lane&31][k=(lane>>5)*8+j];
// C/D col=lane&31, row=(reg&3)+8*(reg>>2)+4*(lane>>5).
// ---------------------------------------------------------------------------
template <int ACT, int RESID, int OMODE>
__global__ __launch_bounds__(256, 2) void gemm_mfma_kernel(
    const ushort* __restrict__ A16, const ushort* __restrict__ W16,
    const float* __restrict__ bias, const float* __restrict__ resid,
    const float* __restrict__ fmask,
    float* __restrict__ outf, ushort* __restrict__ outb) {
  __shared__ __align__(16) ushort As[2][64 * 40];
  int tid = threadIdx.x;
  int w = tid >> 6, lane = tid & 63;
  int m31 = lane & 31, half = lane >> 5;
  int n0 = blockIdx.x * 64;

  floatx16 acc[2][2];
#pragma unroll
  for (int a = 0; a < 2; ++a)
#pragma unroll
    for (int b = 0; b < 2; ++b)
#pragma unroll
      for (int i = 0; i < 16; ++i) acc[a][b][i] = 0.f;

#pragma unroll
  for (int it = 0; it < 2; ++it) {
    int i = tid + it * 256;
    int row = i >> 3, part = i & 7;
    *(uint2*)&As[0][row * 40 + part * 4] =
        *(const uint2*)&A16[(size_t)(n0 + row) * 256 + part * 4];
  }
  bf16x8 bn[2][2];
#pragma unroll
  for (int ks = 0; ks < 2; ++ks)
#pragma unroll
    for (int ct = 0; ct < 2; ++ct)
      bn[ks][ct] = *(const bf16x8*)&W16[(size_t)(w * 64 + ct * 32 + m31) * 256 +
                                        ks * 16 + half * 8];

  for (int c = 0; c < 8; ++c) {
    __syncthreads();
    if (c < 7) {
      int k0 = (c + 1) * 32;
#pragma unroll
      for (int it = 0; it < 2; ++it) {
        int i = tid + it * 256;
        int row = i >> 3, part = i & 7;
        *(uint2*)&As[(c + 1) & 1][row * 40 + part * 4] =
            *(const uint2*)&A16[(size_t)(n0 + row) * 256 + k0 + part * 4];
      }
    }
    bf16x8 bc[2][2];
#pragma unroll
    for (int ks = 0; ks < 2; ++ks)
#pragma unroll
      for (int ct = 0; ct < 2; ++ct) bc[ks][ct] = bn[ks][ct];
    if (c < 7) {
      int k0 = (c + 1) * 32;
#pragma unroll
      for (int ks = 0; ks < 2; ++ks)
#pragma unroll
        for (int ct = 0; ct < 2; ++ct)
          bn[ks][ct] = *(const bf16x8*)&W16[
              (size_t)(w * 64 + ct * 32 + m31) * 256 + k0 + ks * 16 + half * 8];
    }
    const ushort* ab = As[c & 1];
#pragma unroll
    for (int ks = 0; ks < 2; ++ks) {
      bf16x8 af[2];
#pragma unroll
      for (int rt = 0; rt < 2; ++rt)
        af[rt] = *(const bf16x8*)&ab[(rt * 32 + m31) * 40 + ks * 16 + half * 8];
#pragma unroll
      for (int rt = 0; rt < 2; ++rt)
#pragma unroll
        for (int ct = 0; ct < 2; ++ct)
          acc[rt][ct] = __builtin_amdgcn_mfma_f32_32x32x16_bf16(
              af[rt], bc[ks][ct], acc[rt][ct], 0, 0, 0);
    }
  }
  if (OMODE == 3) {
    // masked pooling epilogue: psum[ct] = sum over unmasked rows of v
    int b = n0 >> 10;
    float psum[2] = {0.f, 0.f};
    float bv0 = bias[w * 64 + m31], bv1 = bias[w * 64 + 32 + m31];
#pragma unroll
    for (int rt = 0; rt < 2; ++rt) {
#pragma unroll
      for (int reg = 0; reg < 16; ++reg) {
        int row = n0 + rt * 32 + (reg & 3) + 8 * (reg >> 2) + 4 * half;
        float keep = (fmask[row] == 0.f) ? 1.f : 0.f;
        float r0 = resid[(size_t)row * 256 + w * 64 + m31];
        float r1 = resid[(size_t)row * 256 + w * 64 + 32 + m31];
        psum[0] += keep * (acc[rt][0][reg] + bv0 + r0);
        psum[1] += keep * (acc[rt][1][reg] + bv1 + r1);
      }
    }
    atomicAdd(&outf[b * 256 + w * 64 + m31], psum[0]);
    atomicAdd(&outf[b * 256 + w * 64 + 32 + m31], psum[1]);
    return;
  }
#pragma unroll
  for (int ct = 0; ct < 2; ++ct) {
    int col = w * 64 + ct * 32 + m31;
    float bv = bias[col];
#pragma unroll
    for (int rt = 0; rt < 2; ++rt) {
#pragma unroll
      for (int reg = 0; reg < 16; ++reg) {
        int row = n0 + rt * 32 + (reg & 3) + 8 * (reg >> 2) + 4 * half;
        float v = acc[rt][ct][reg] + bv;
        if (ACT == 1) v = mishf_(v);
        if (RESID) v += resid[(size_t)row * 256 + col];
        if (OMODE == 0) {
          outf[(size_t)row * 256 + col] = v;
        } else if (OMODE == 1) {
          outb[(size_t)row * 256 + col] = f2bf_(v);
        } else {
          outf[(size_t)row * 256 + col] = v;
          outb[(size_t)row * 256 + col] = f2bf_(v);
        }
      }
    }
  }
}

// ---------------------------------------------------------------------------
// Fused QKV projection. grid (256, 3): by 0=Q->QE (x1/16), 1=K->KF, 2=V->VF.
// ---------------------------------------------------------------------------
__global__ __launch_bounds__(256, 2) void qkv_mfma_kernel(
    const ushort* __restrict__ A16, const ushort* __restrict__ wqkv,
    const float* __restrict__ bq, const float* __restrict__ bk,
    const float* __restrict__ bv,
    ushort* __restrict__ QE, ushort* __restrict__ KF, ushort* __restrict__ VF) {
  __shared__ __align__(16) ushort As[2][64 * 40];
  int tid = threadIdx.x;
  int w = tid >> 6, lane = tid & 63;
  int m31 = lane & 31, half = lane >> 5;
  int n0 = blockIdx.x * 64;
  int by = blockIdx.y;
  const ushort* W16 = wqkv + (size_t)by * 65536;
  const float* bias = (by == 0) ? bq : (by == 1) ? bk : bv;

  floatx16 acc[2][2];
#pragma unroll
  for (int a = 0; a < 2; ++a)
#pragma unroll
    for (int b = 0; b < 2; ++b)
#pragma unroll
      for (int i = 0; i < 16; ++i) acc[a][b][i] = 0.f;

#pragma unroll
  for (int it = 0; it < 2; ++it) {
    int i = tid + it * 256;
    int row = i >> 3, part = i & 7;
    *(uint2*)&As[0][row * 40 + part * 4] =
        *(const uint2*)&A16[(size_t)(n0 + row) * 256 + part * 4];
  }
  bf16x8 bn[2][2];
#pragma unroll
  for (int ks = 0; ks < 2; ++ks)
#pragma unroll
    for (int ct = 0; ct < 2; ++ct)
      bn[ks][ct] = *(const bf16x8*)&W16[(size_t)(w * 64 + ct * 32 + m31) * 256 +
                                        ks * 16 + half * 8];
  for (int c = 0; c < 8; ++c) {
    __syncthreads();
    if (c < 7) {
      int k0 = (c + 1) * 32;
#pragma unroll
      for (int it = 0; it < 2; ++it) {
        int i = tid + it * 256;
        int row = i >> 3, part = i & 7;
        *(uint2*)&As[(c + 1) & 1][row * 40 + part * 4] =
            *(const uint2*)&A16[(size_t)(n0 + row) * 256 + k0 + part * 4];
      }
    }
    bf16x8 bc[2][2];
#pragma unroll
    for (int ks = 0; ks < 2; ++ks)
#pragma unroll
      for (int ct = 0; ct < 2; ++ct) bc[ks][ct] = bn[ks][ct];
    if (c < 7) {
      int k0 = (c + 1) * 32;
#pragma unroll
      for (int ks = 0; ks < 2; ++ks)
#pragma unroll
        for (int ct = 0; ct < 2; ++ct)
          bn[ks][ct] = *(const bf16x8*)&W16[
              (size_t)(w * 64 + ct * 32 + m31) * 256 + k0 + ks * 16 + half * 8];
    }
    const ushort* ab = As[c & 1];
#pragma unroll
    for (int ks = 0; ks < 2; ++ks) {
      bf16x8 af[2];
#pragma unroll
      for (int rt = 0; rt < 2; ++rt)
        af[rt] = *(const bf16x8*)&ab[(rt * 32 + m31) * 40 + ks * 16 + half * 8];
#pragma unroll
      for (int rt = 0; rt < 2; ++rt)
#pragma unroll
        for (int ct = 0; ct < 2; ++ct)
          acc[rt][ct] = __builtin_amdgcn_mfma_f32_32x32x16_bf16(
              af[rt], bc[ks][ct], acc[rt][ct], 0, 0, 0);
    }
  }
  int b = n0 >> 10;
#pragma unroll
  for (int ct = 0; ct < 2; ++ct) {
    int col = w * 64 + ct * 32 + m31;
    float bvv = bias[col];
    int h = col >> 7, d127 = col & 127;
    int bh = b * 2 + h;
    if (by == 2) {  // VF frag-major, ushort4 stores
      int ctv = d127 >> 5, m31v = d127 & 31;
#pragma unroll
      for (int rt = 0; rt < 2; ++rt)
#pragma unroll
        for (int rg = 0; rg < 4; ++rg) {
          int t0 = (n0 & 1023) + rt * 32 + 8 * rg + 4 * half;
          ushort4 u;
          u.x = f2bf_(acc[rt][ct][rg * 4 + 0] + bvv);
          u.y = f2bf_(acc[rt][ct][rg * 4 + 1] + bvv);
          u.z = f2bf_(acc[rt][ct][rg * 4 + 2] + bvv);
          u.w = f2bf_(acc[rt][ct][rg * 4 + 3] + bvv);
          size_t addr = ((size_t)(bh * 16 + (t0 >> 6)) * 16 +
                         ((t0 >> 4) & 3) * 4 + ctv) * 512 +
                        m31v * 16 + ((t0 >> 3) & 1) * 8 + (t0 & 7);
          *(ushort4*)&VF[addr] = u;
        }
    } else {
#pragma unroll
      for (int rt = 0; rt < 2; ++rt)
#pragma unroll
        for (int reg = 0; reg < 16; ++reg) {
          int t = (n0 & 1023) + rt * 32 + (reg & 3) + 8 * (reg >> 2) + 4 * half;
          float v = acc[rt][ct][reg] + bvv;
          if (by == 0) {
            QE[((size_t)(bh * 1024 + t)) * 144 + d127] = f2bf_(v * 0.0625f);
          } else {
            size_t addr = ((size_t)(bh * 32 + (t >> 5)) * 9 + (d127 >> 4)) * 512 +
                          (t & 31) * 16 + ((d127 >> 3) & 1) * 8 + (d127 & 7);
            KF[addr] = f2bf_(v);
          }
        }
    }
  }
}

// ---------------------------------------------------------------------------
// Conv1dGLU bf16 MFMA, in-lane GLU (unchanged from round 5).
// ---------------------------------------------------------------------------
template <int DO_MASK>
__global__ __launch_bounds__(256, 2) void conv_mfma_kernel(
    const ushort* __restrict__ H16, const float* __restrict__ Hf,
    const ushort* __restrict__ WtF, const float* __restrict__ cb,
    const float* __restrict__ fmask, float* __restrict__ outf,
    ushort* __restrict__ outb) {
  __shared__ __align__(16) ushort As[2][132 * 40];
  int tid = threadIdx.x;
  int w = tid >> 6, lane = tid & 63;
  int m31 = lane & 31, half = lane >> 5;
  int wr = w >> 1, wc = w & 1;
  int cg = blockIdx.x;
  int n0 = blockIdx.y * 128;
  int tbase = n0 & 1023;
  int acol = cg * 64 + wc * 32;
  int cotA = cg * 2 + wc, cotG = 8 + cg * 2 + wc;

  floatx16 acc[2][2];
#pragma unroll
  for (int a = 0; a < 2; ++a)
#pragma unroll
    for (int b = 0; b < 2; ++b)
#pragma unroll
      for (int i = 0; i < 16; ++i) acc[a][b][i] = 0.f;

  for (int i = tid; i < 1056; i += 256) {
    int row = i >> 3, part = i & 7;
    int t = tbase + row - 2;
    uint2 v = make_uint2(0u, 0u);
    if ((unsigned)t < 1024u)
      v = *(const uint2*)&H16[(size_t)(n0 + row - 2) * 256 + part * 4];
    *(uint2*)&As[0][row * 40 + part * 4] = v;
  }
  bf16x8 bn[2][2];
#pragma unroll
  for (int ks = 0; ks < 2; ++ks) {
    bn[ks][0] = *(const bf16x8*)&WtF[(size_t)(((cotA * 5 + 0) * 8 + 0) * 2 + ks) * 512 +
                                     m31 * 16 + half * 8];
    bn[ks][1] = *(const bf16x8*)&WtF[(size_t)(((cotG * 5 + 0) * 8 + 0) * 2 + ks) * 512 +
                                     m31 * 16 + half * 8];
  }

  for (int c = 0; c < 8; ++c) {
    __syncthreads();
    if (c < 7) {
      int k0 = (c + 1) * 32;
      for (int i = tid; i < 1056; i += 256) {
        int row = i >> 3, part = i & 7;
        int t = tbase + row - 2;
        uint2 v = make_uint2(0u, 0u);
        if ((unsigned)t < 1024u)
          v = *(const uint2*)&H16[(size_t)(n0 + row - 2) * 256 + k0 + part * 4];
        *(uint2*)&As[(c + 1) & 1][row * 40 + part * 4] = v;
      }
    }
    const ushort* ab = As[c & 1];
#pragma unroll
    for (int tap = 0; tap < 5; ++tap) {
      bf16x8 bc[2][2];
#pragma unroll
      for (int ks = 0; ks < 2; ++ks)
#pragma unroll
        for (int ct = 0; ct < 2; ++ct) bc[ks][ct] = bn[ks][ct];
      int pc = c, pt = tap + 1;
      if (pt == 5) { pc = c + 1; pt = 0; }
      if (pc < 8) {
#pragma unroll
        for (int ks = 0; ks < 2; ++ks) {
          bn[ks][0] = *(const bf16x8*)&WtF[
              (size_t)(((cotA * 5 + pt) * 8 + pc) * 2 + ks) * 512 + m31 * 16 + half * 8];
          bn[ks][1] = *(const bf16x8*)&WtF[
              (size_t)(((cotG * 5 + pt) * 8 + pc) * 2 + ks) * 512 + m31 * 16 + half * 8];
        }
      }
#pragma unroll
      for (int ks = 0; ks < 2; ++ks) {
        bf16x8 af[2];
#pragma unroll
        for (int rt = 0; rt < 2; ++rt)
          af[rt] = *(const bf16x8*)&ab[(wr * 64 + rt * 32 + m31 + tap) * 40 +
                                       ks * 16 + half * 8];
#pragma unroll
        for (int rt = 0; rt < 2; ++rt)
#pragma unroll
          for (int ct = 0; ct < 2; ++ct)
            acc[rt][ct] = __builtin_amdgcn_mfma_f32_32x32x16_bf16(
                af[rt], bc[ks][ct], acc[rt][ct], 0, 0, 0);
      }
    }
  }
  int col = acol + m31;
  float ba = cb[col], bg = cb[256 + col];
#pragma unroll
  for (int rt = 0; rt < 2; ++rt) {
#pragma unroll
    for (int reg = 0; reg < 16; ++reg) {
      int brow = wr * 64 + rt * 32 + (reg & 3) + 8 * (reg >> 2) + 4 * half;
      int grow = n0 + brow;
      float a = acc[rt][0][reg] + ba;
      float g = acc[rt][1][reg] + bg;
      float v = Hf[(size_t)grow * 256 + col] + a * sigmoidf_(g);
      if (DO_MASK) {
        if (fmask[grow] != 0.f) v = 0.f;
      }
      outf[(size_t)grow * 256 + col] = v;
      outb[(size_t)grow * 256 + col] = f2bf_(v);
    }
  }
}

// ---------------------------------------------------------------------------
// LDS-free bf16 MFMA flash attention, XCD-aware grid: x = bh (32), y = qtile
// (16). Blocks sharing a bh are 32 IDs apart -> same XCD under round-robin
// dispatch -> K/V L2-resident (4 bh x ~560 KB per XCD).
// ---------------------------------------------------------------------------
__global__ __launch_bounds__(256, 2) void attn_mfma2_kernel(
    const ushort* __restrict__ QE, const ushort* __restrict__ KF,
    const ushort* __restrict__ VF, ushort* __restrict__ O) {
  __shared__ float Op[2][128][33];
  __shared__ float Ml[2][2][32];
  int tid = threadIdx.x;
  int w = tid >> 6, lane = tid & 63;
  int m31 = lane & 31, half = lane >> 5;
  int qt = w & 1, kh = w >> 1;
  int bh = blockIdx.x;
  int q0 = blockIdx.y * 64 + qt * 32;
  int lpos = m31 * 16 + half * 8;

  bf16x8 qe[9];
  {
    size_t qrow = ((size_t)(bh * 1024 + q0 + m31)) * 144;
#pragma unroll
    for (int c = 0; c < 9; ++c)
      qe[c] = *(const bf16x8*)&QE[qrow + c * 16 + half * 8];
  }
  floatx16 oacc[4];
#pragma unroll
  for (int ct = 0; ct < 4; ++ct)
#pragma unroll
    for (int i = 0; i < 16; ++i) oacc[ct][i] = 0.f;
  float mi = -1e30f, li = 0.f;

  for (int it = 0; it < 8; ++it) {
    int ktb = kh * 512 + it * 64;
    int kfrag = (bh * 32 + (ktb >> 5)) * 9;
    int vtile = (bh * 16 + (ktb >> 6)) * 16;
    floatx16 s0, s1;
#pragma unroll
    for (int i = 0; i < 16; ++i) { s0[i] = 0.f; s1[i] = 0.f; }
#pragma unroll
    for (int c = 0; c < 9; ++c) {
      bf16x8 kf0 = *(const bf16x8*)&KF[(size_t)(kfrag + c) * 512 + lpos];
      bf16x8 kf1 = *(const bf16x8*)&KF[(size_t)(kfrag + 9 + c) * 512 + lpos];
      s0 = __builtin_amdgcn_mfma_f32_32x32x16_bf16(kf0, qe[c], s0, 0, 0, 0);
      s1 = __builtin_amdgcn_mfma_f32_32x32x16_bf16(kf1, qe[c], s1, 0, 0, 0);
    }
    bf16x8 vfr[2][4];
#pragma unroll
    for (int s2 = 0; s2 < 2; ++s2)
#pragma unroll
      for (int ct = 0; ct < 4; ++ct)
        vfr[s2][ct] = *(const bf16x8*)&VF[(size_t)(vtile + s2 * 4 + ct) * 512 + lpos];
    float mloc = s0[0];
#pragma unroll
    for (int r = 1; r < 16; ++r) mloc = fmaxf(mloc, s0[r]);
#pragma unroll
    for (int r = 0; r < 16; ++r) mloc = fmaxf(mloc, s1[r]);
    float mt = fmaxf(mloc, __shfl_xor(mloc, 32));
    float mnew = fmaxf(mi, mt);
    float alpha = __expf(mi - mnew);
    bool dead = (mnew <= -3.0e4f);
    float sum = 0.f;
#pragma unroll
    for (int r = 0; r < 16; ++r) {
      float v0 = dead ? 0.f : __expf(s0[r] - mnew);
      float v1 = dead ? 0.f : __expf(s1[r] - mnew);
      s0[r] = v0; s1[r] = v1;
      sum += v0 + v1;
    }
    sum += __shfl_xor(sum, 32);
    li = li * alpha + sum;
    mi = mnew;
#pragma unroll
    for (int ct = 0; ct < 4; ++ct)
#pragma unroll
      for (int i = 0; i < 16; ++i) oacc[ct][i] *= alpha;
    bf16x8 pf[4];
#pragma unroll
    for (int sub = 0; sub < 2; ++sub) {
      float tx[16];
#pragma unroll
      for (int r = 0; r < 16; ++r)
        tx[r] = __shfl_xor(sub == 0 ? s0[r] : s1[r], 32);
#pragma unroll
      for (int s = 0; s < 2; ++s) {
        union { bf16x8 v; ushort u[8]; } pk;
#pragma unroll
        for (int j = 0; j < 8; ++j) {
          int base = s * 8;
          float own = (sub == 0) ? s0[base + j] : s1[base + j];
          float lo = (j < 4) ? own : tx[base + j - 4];
          float hi = (j < 4) ? tx[base + 4 + j] : own;
          pk.u[j] = f2bf_(half ? hi : lo);
        }
        pf[sub * 2 + s] = pk.v;
      }
    }
#pragma unroll
    for (int s2 = 0; s2 < 4; ++s2)
#pragma unroll
      for (int ct = 0; ct < 4; ++ct) {
        bf16x8 vf = (s2 < 2) ? vfr[s2][ct]
                  : *(const bf16x8*)&VF[(size_t)(vtile + s2 * 4 + ct) * 512 + lpos];
        oacc[ct] = __builtin_amdgcn_mfma_f32_32x32x16_bf16(
            vf, pf[s2], oacc[ct], 0, 0, 0);
      }
  }
  if (kh == 1) {
#pragma unroll
    for (int ct = 0; ct < 4; ++ct)
#pragma unroll
      for (int r = 0; r < 16; ++r) {
        int dv = ct * 32 + (r & 3) + 8 * (r >> 2) + 4 * half;
        Op[qt][dv][m31] = oacc[ct][r];
      }
    if (half == 0) { Ml[qt][0][m31] = mi; Ml[qt][1][m31] = li; }
  }
  __syncthreads();
  if (kh == 0) {
    float mB = Ml[qt][0][m31], lB = Ml[qt][1][m31];
    float m = fmaxf(mi, mB);
    float aA = __expf(mi - m), aB = __expf(mB - m);
    float l = li * aA + lB * aB;
    float inv = (l > 0.f) ? 1.f / l : 0.f;
    int b = bh >> 1, h = bh & 1;
    size_t rowbase = (size_t)(b * 1024 + q0 + m31) * 256 + h * 128;
#pragma unroll
    for (int ct = 0; ct < 4; ++ct)
#pragma unroll
      for (int rg = 0; rg < 4; ++rg) {
        int dv0 = ct * 32 + 8 * rg + 4 * half;
        ushort4 u;
        u.x = f2bf_((oacc[ct][rg * 4 + 0] * aA + Op[qt][dv0 + 0][m31] * aB) * inv);
        u.y = f2bf_((oacc[ct][rg * 4 + 1] * aA + Op[qt][dv0 + 1][m31] * aB) * inv);
        u.z = f2bf_((oacc[ct][rg * 4 + 2] * aA + Op[qt][dv0 + 2][m31] * aB) * inv);
        u.w = f2bf_((oacc[ct][rg * 4 + 3] * aA + Op[qt][dv0 + 3][m31] * aB) * inv);
        *(ushort4*)&O[rowbase + dv0] = u;
      }
  }
}

// ---------------------------------------------------------------------------
// Final projection: out[b][j] = dot(pooled[b,:], Wf[j,:]) / len[b] + bf[j].
// ---------------------------------------------------------------------------
__global__ __launch_bounds__(256) void final_kernel(
    const float* __restrict__ pooled, const float* __restrict__ fmask,
    const float* __restrict__ Wf, const float* __restrict__ bf,
    float* __restrict__ out) {
  int b = blockIdx.x, j = threadIdx.x;
  __shared__ __align__(16) float p[256];
  __shared__ float red[256];
  p[j] = pooled[b * 256 + j];
  float c = 0.f;
  for (int i = 0; i < 4; ++i)
    c += (fmask[b * 1024 + i * 256 + j] == 0.f) ? 1.f : 0.f;
  red[j] = c;
  __syncthreads();
  for (int st = 128; st > 0; st >>= 1) {
    if (j < st) red[j] += red[j + st];
    __syncthreads();
  }
  float len = red[0];
  const float* wrow = Wf + (size_t)j * 256;
  float acc = 0.f;
  for (int d4 = 0; d4 < 64; ++d4) {
    float4 wv = ((const float4*)wrow)[d4];
    float4 pv = ((const float4*)p)[d4];
    acc += wv.x * pv.x + wv.y * pv.y + wv.z * pv.z + wv.w * pv.w;
  }
  float inv = (len > 0.f) ? 1.f / len : 0.f;
  out[b * 256 + j] = acc * inv + bf[j];
}

// ---------------------------------------------------------------------------
extern "C" void kernel_launch(void* const* d_in, const int* in_sizes, int n_in,
                              void* d_out, int out_size, void* d_ws, size_t ws_size,
                              hipStream_t stream) {
  const float* x      = (const float*)d_in[0];
  const unsigned* msk = (const unsigned*)d_in[1];
  const float* W1 = (const float*)d_in[2];
  const float* b1 = (const float*)d_in[3];
  const float* W2 = (const float*)d_in[4];
  const float* b2 = (const float*)d_in[5];
  const float* cW1 = (const float*)d_in[6];
  const float* cb1 = (const float*)d_in[7];
  const float* cW2 = (const float*)d_in[8];
  const float* cb2 = (const float*)d_in[9];
  const float* Wq = (const float*)d_in[10];
  const float* bq = (const float*)d_in[11];
  const float* Wk = (const float*)d_in[12];
  const float* bk = (const float*)d_in[13];
  const float* Wv = (const float*)d_in[14];
  const float* bv = (const float*)d_in[15];
  const float* Wo = (const float*)d_in[16];
  const float* bo = (const float*)d_in[17];
  const float* Wf = (const float*)d_in[18];
  const float* bf = (const float*)d_in[19];
  float* out = (float*)d_out;

  float* ws = (float*)d_ws;
  size_t ND = (size_t)N_ * D_;  // 4194304
  float* F0      = ws;
  float* F1      = F0 + ND;
  float* fmask   = F1 + ND;
  float* pooled  = fmask + N_;           // [16*256]
  ushort* G0 = (ushort*)(pooled + 16 * 256);
  ushort* G1 = G0 + ND;
  ushort* QE = G1 + ND;                  // [32*1024*144]
  ushort* KF = QE + (size_t)32 * 1024 * 144;   // [32*32*9*512]
  ushort* VF = KF + (size_t)32 * 32 * 9 * 512; // [32*16*16*512]
  ushort* w1_16 = VF + (size_t)32 * 16 * 16 * 512;
  ushort* w2_16 = w1_16 + 65536;
  ushort* wo_16 = w2_16 + 65536;
  ushort* wqkv  = wo_16 + 65536;         // 3 x 65536
  ushort* WtF1  = wqkv + 3 * 65536;      // [655360]
  ushort* WtF2  = WtF1 + 655360;

  dim3 blk(256);
  prep_all_kernel<<<dim3(9728), blk, 0, stream>>>(
      x, msk, W1, W2, Wq, Wk, Wv, Wo, cW1, cW2,
      G0, w1_16, w2_16, wqkv, wo_16, WtF1, WtF2, fmask, QE, KF, pooled);
  // spectral MLP
  gemm_mfma_kernel<1, 0, 1><<<dim3(256), blk, 0, stream>>>(
      G0, w1_16, b1, nullptr, nullptr, nullptr, G1);
  gemm_mfma_kernel<1, 0, 2><<<dim3(256), blk, 0, stream>>>(
      G1, w2_16, b2, nullptr, nullptr, F0, G0);
  // conv GLU x2 (second fuses mask-zeroing)
  conv_mfma_kernel<0><<<dim3(4, 128), blk, 0, stream>>>(
      G0, F0, WtF1, cb1, fmask, F1, G1);
  conv_mfma_kernel<1><<<dim3(4, 128), blk, 0, stream>>>(
      G1, F1, WtF2, cb2, fmask, F0, G0);
  // fused QKV into QE/KF/VF layouts
  qkv_mfma_kernel<<<dim3(256, 3), blk, 0, stream>>>(
      G0, wqkv, bq, bk, bv, QE, KF, VF);
  // attention, XCD-aware grid (x = bh)
  attn_mfma2_kernel<<<dim3(32, 16), blk, 0, stream>>>(QE, KF, VF, G1);
  // out-proj + residual + masked pooling (h5 never materialized)
  gemm_mfma_kernel<0, 1, 3><<<dim3(256), blk, 0, stream>>>(
      G1, wo_16, bo, F0, fmask, pooled, nullptr);
  // final projection
  final_kernel<<<dim3(16), blk, 0, stream>>>(pooled, fmask, Wf, bf, out);
}